// Round 7
// baseline (311.894 us; speedup 1.0000x reference)
//
#include <hip/hip_runtime.h>
#include <cmath>

// ---------------------------------------------------------------------------
// Classifier pipeline. Main GEMMs: fp16x1, 8-phase counted-vmcnt schedule
// (T3+T4+T5, m198-class), 256x128 tile, 8 waves, triple-buffered LDS.
// Argmax protected by fp16x2 correction chain on flagged rows (top-2 gap
// < TAU), K-split partials (round-6 structure, old m97 kernel).
//
// d_out byte layout (total 165,412,864 B):
//   feats [8192,1024] f32 @ 0
//   aug   [8192,1024] f32 @ 33,554,432
//   o1    [8192,1000] f32 @ 67,108,864
//   o2    [8192,1000] f32 @ 99,876,864
//   smx   [8192,1000] f32 @ 132,644,864
//
// Scratch (dead-region hosted; lifetime [first-write .. last-read]):
//   fh    fp16[8192*2048] @  67,108,864  [convF .. G1]       (o1 slot)
//   fetsh fp16[8192*1024] @  33,554,432  [G1 .. G2]          (aug slot)
//   P1    f32[4*1024*1024]@  33,554,432  [gG1 .. red1]       (aug slot, fetsh dead)
//   P2    f32[2*1024*1000]@  33,554,432  [gG2 .. fixup]      (aug slot, P1 dead)
//   idx   int[1024]       @  50,331,648  [masksm .. fixup]
//   cnt   int             @  50,339,840  [zero .. fixup]
//   fgsh  fp16[1024*1024] @  50,348,032  [red1 .. gG2]
//   fgsl  fp16[1024*1024] @  52,445,184  [red1 .. gG2]
//   sm1h  fp16[8192*1024] @  99,876,864  [masksm .. G3]      (o2 slot)
//   cth   fp16[1024*1024] @ 116,654,080  [ctrans .. G3]
//   wbh   fp16[1024*2048] @ 118,751,232  [splitWb .. gG1]
//   wbl   fp16[1024*2048] @ 122,945,536  [splitWb .. gG1]
//   w2h   fp16[1024*1024] @ 132,644,864  [padW2 .. G4]       (smx slot)
//   w1h   fp16[1024*1024] @ 142,606,336  [padW1 .. gG2]
//   w1l   fp16[1024*1024] @ 144,703,488  [padW1 .. gG2]
//   fgh   fp16[1024*2048] @ 146,800,640  [gather .. gG1]
//   fgl   fp16[1024*2048] @ 150,994,944  [gather .. gG1]
//   xh    fp16[8192*1024] @ 146,800,640  [rownorm .. G4]     (fgh/fgl dead)
// ---------------------------------------------------------------------------

typedef _Float16 h8 __attribute__((ext_vector_type(8)));
typedef _Float16 h4 __attribute__((ext_vector_type(4)));
typedef float f32x4 __attribute__((ext_vector_type(4)));

#define TAU 0.015f
#define CAP 1024

__device__ __forceinline__ void gload_lds16(const _Float16* g, _Float16* l) {
    __builtin_amdgcn_global_load_lds(
        (const __attribute__((address_space(1))) void*)g,
        (__attribute__((address_space(3))) void*)l, 16, 0, 0);
}

__global__ void zero_cnt_kernel(int* __restrict__ cnt) { *cnt = 0; }

// ===========================================================================
// Main GEMM: 8-phase counted-vmcnt schedule. C = A@B^T (+mode epilogue).
// BM=256, BN=128, BK=64; 8 waves (2Mx4N, 128x32 out each); LDS 3-buffered.
// MODE 1: C = A@B^T + bias(aux); also Ch = fp16(C)
// MODE 2: C = A@B^T, cols<nC
// MODE 3: C = A@B^T + aux[row,col]
// MODE 4: C = A@B^T * 20, cols<nC
// ===========================================================================
template <int MODE>
__global__ __launch_bounds__(512, 1) void gemm8p(
    const _Float16* __restrict__ Ah, int lda,
    const _Float16* __restrict__ Bh, int ldb, int K,
    float* __restrict__ C, int ldc, int nC,
    const float* __restrict__ aux, _Float16* __restrict__ Ch)
{
    __shared__ _Float16 sA[3][256 * 64];
    __shared__ _Float16 sB[3][128 * 64];

    const int t = threadIdx.x;
    const int lane = t & 63, wid = t >> 6;
    // bijective XCD chunking: 256 wgs, 32/XCD -> 4 row-panels x 8 col-panels
    const int wg = blockIdx.x;
    const int wgid = (wg & 7) * 32 + (wg >> 3);
    const int row0 = (wgid >> 3) * 256, col0 = (wgid & 7) * 128;
    const int wr = wid >> 2, wc = wid & 3;     // 2x4 waves
    const int fr = lane & 15;
    const int fk = (lane >> 4) * 8;
    const int srow = lane >> 3;                // staging: 8 lanes/row
    const int scol = (lane & 7) * 8;           // 16B per lane

    f32x4 acc[8][2] = {};

    // stage one third of tile kt into buffer b (phase 0/1: A halves, 2: B)
    auto stage = [&](int b, int kt, int ph) {
        const int kk = kt * 64;
        if (ph == 0 || ph == 1) {
            #pragma unroll
            for (int j = 0; j < 2; ++j) {
                const int i = wid * 4 + ph * 2 + j;          // A issue 0..31
                const int r = i * 8 + srow;
                gload_lds16(Ah + (size_t)(row0 + r) * lda + kk + scol, &sA[b][i * 512]);
            }
        } else if (ph == 2) {
            #pragma unroll
            for (int j = 0; j < 2; ++j) {
                const int i = wid * 2 + j;                   // B issue 0..15
                const int r = i * 8 + srow;
                gload_lds16(Bh + (size_t)(col0 + r) * ldb + kk + scol, &sB[b][i * 512]);
            }
        }
    };

    const int NT = K >> 6;
    // prologue: stage tiles 0 and 1
    #pragma unroll
    for (int ph = 0; ph < 3; ++ph) stage(0, 0, ph);
    #pragma unroll
    for (int ph = 0; ph < 3; ++ph) stage(1, 1, ph);
    asm volatile("s_waitcnt vmcnt(6)" ::: "memory");   // tile 0 landed
    __builtin_amdgcn_s_barrier();

    for (int kt = 0; kt < NT; ++kt) {
        const int cb = kt % 3;
        const int pb = (kt + 2) % 3;
        const bool pf = (kt + 2) < NT;
        h8 b0, b1;
        #pragma unroll
        for (int ph = 0; ph < 4; ++ph) {
            const int ks = ph >> 1, mh = ph & 1;
            // ---- ds-read this phase's fragments ----
            if (mh == 0) {
                b0 = *(const h8*)&sB[cb][(wc * 32 + fr) * 64 + ks * 32 + fk];
                b1 = *(const h8*)&sB[cb][(wc * 32 + 16 + fr) * 64 + ks * 32 + fk];
            }
            h8 af[4];
            #pragma unroll
            for (int i = 0; i < 4; ++i)
                af[i] = *(const h8*)&sA[cb][(wr * 128 + (mh * 4 + i) * 16 + fr) * 64 + ks * 32 + fk];
            // ---- issue prefetch for tile kt+2 ----
            if (pf) stage(pb, kt + 2, ph);                   // ph==3: no-op
            if (ph == 3) {
                if (pf)             asm volatile("s_waitcnt vmcnt(6)" ::: "memory"); // tile kt+1 landed
                else if (kt + 1 < NT) asm volatile("s_waitcnt vmcnt(0)" ::: "memory"); // drain tail
            }
            __builtin_amdgcn_s_barrier();
            asm volatile("s_waitcnt lgkmcnt(0)" ::: "memory");
            __builtin_amdgcn_s_setprio(1);
            #pragma unroll
            for (int i = 0; i < 4; ++i) {
                acc[mh * 4 + i][0] = __builtin_amdgcn_mfma_f32_16x16x32_f16(af[i], b0, acc[mh * 4 + i][0], 0, 0, 0);
                acc[mh * 4 + i][1] = __builtin_amdgcn_mfma_f32_16x16x32_f16(af[i], b1, acc[mh * 4 + i][1], 0, 0, 0);
            }
            __builtin_amdgcn_s_setprio(0);
            __builtin_amdgcn_s_barrier();
        }
    }

    // ---- epilogue (C/D: col=lane&15, row=(lane>>4)*4+j) ----
    #pragma unroll
    for (int mf = 0; mf < 8; ++mf) {
        #pragma unroll
        for (int nf = 0; nf < 2; ++nf) {
            f32x4 v = acc[mf][nf];
            const int gcol = col0 + wc * 32 + nf * 16 + fr;
            const int rbase = row0 + wr * 128 + mf * 16 + (lane >> 4) * 4;
            #pragma unroll
            for (int j = 0; j < 4; ++j) {
                const int grow = rbase + j;
                float val = v[j];
                if constexpr (MODE == 1) val += aux[gcol];
                if constexpr (MODE == 3) val += aux[(size_t)grow * 1024 + gcol];
                if constexpr (MODE == 4) val *= 20.0f;
                if (gcol < nC) {
                    C[(size_t)grow * ldc + gcol] = val;
                    if constexpr (MODE == 1)
                        Ch[(size_t)grow * 1024 + gcol] = (_Float16)val;
                }
            }
        }
    }
}

// ===========================================================================
// Chain GEMM (old m97 structure, fp16x2, K-split partials, early-exit on cnt)
// ===========================================================================
__global__ __launch_bounds__(256, 2) void gemmc(
    const _Float16* __restrict__ Ah, const _Float16* __restrict__ Al, int lda,
    const _Float16* __restrict__ Bh, const _Float16* __restrict__ Bl, int ldb,
    int klen,
    float* __restrict__ C, int ldc, int nC,
    const int* __restrict__ cnt)
{
    __shared__ _Float16 sAh[128 * 64];
    __shared__ _Float16 sBh[128 * 64];
    __shared__ _Float16 sAl[128 * 64];
    __shared__ _Float16 sBl[128 * 64];

    const int t = threadIdx.x;
    const int lane = t & 63, wid = t >> 6;
    const int row0 = blockIdx.y * 128, col0 = blockIdx.x * 128;
    const int kbase = blockIdx.z * klen;
    if (row0 >= *cnt) return;
    const int wr = wid >> 1, wc = wid & 1;
    const int fr = lane & 15;
    const int fk = (lane >> 4) * 8;
    const int srow = lane >> 3;
    const int scol = (lane & 7) * 8;

    f32x4 acc[4][4] = {};
    f32x4 accc[4][4] = {};

    for (int k0 = kbase; k0 < kbase + klen; k0 += 64) {
        #pragma unroll
        for (int j = 0; j < 4; ++j) {
            int i = wid * 4 + j;
            int r = i * 8 + srow;
            const size_t ga = (size_t)(row0 + r) * lda + k0 + scol;
            const size_t gb = (size_t)(col0 + r) * ldb + k0 + scol;
            gload_lds16(Ah + ga, &sAh[i * 512]);
            gload_lds16(Bh + gb, &sBh[i * 512]);
            gload_lds16(Al + ga, &sAl[i * 512]);
            gload_lds16(Bl + gb, &sBl[i * 512]);
        }
        __syncthreads();
        #pragma unroll
        for (int ks = 0; ks < 2; ++ks) {
            h8 ah[4], al[4];
            #pragma unroll
            for (int mf = 0; mf < 4; ++mf) {
                int rr = wr * 64 + mf * 16 + fr;
                ah[mf] = *(const h8*)&sAh[rr * 64 + ks * 32 + fk];
                al[mf] = *(const h8*)&sAl[rr * 64 + ks * 32 + fk];
            }
            #pragma unroll
            for (int nf = 0; nf < 4; ++nf) {
                int cc = wc * 64 + nf * 16 + fr;
                h8 bh = *(const h8*)&sBh[cc * 64 + ks * 32 + fk];
                h8 bl = *(const h8*)&sBl[cc * 64 + ks * 32 + fk];
                #pragma unroll
                for (int mf = 0; mf < 4; ++mf) {
                    acc[mf][nf]  = __builtin_amdgcn_mfma_f32_16x16x32_f16(ah[mf], bh, acc[mf][nf], 0, 0, 0);
                    accc[mf][nf] = __builtin_amdgcn_mfma_f32_16x16x32_f16(ah[mf], bl, accc[mf][nf], 0, 0, 0);
                    accc[mf][nf] = __builtin_amdgcn_mfma_f32_16x16x32_f16(al[mf], bh, accc[mf][nf], 0, 0, 0);
                }
            }
        }
        __syncthreads();
    }
    float* Cz = C + (size_t)blockIdx.z * CAP * ldc;
    #pragma unroll
    for (int mf = 0; mf < 4; ++mf) {
        #pragma unroll
        for (int nf = 0; nf < 4; ++nf) {
            f32x4 v = acc[mf][nf] + accc[mf][nf] * (1.0f / 2048.0f);
            const int gcol = col0 + wc * 64 + nf * 16 + fr;
            const int rbase = row0 + wr * 64 + mf * 16 + (lane >> 4) * 4;
            #pragma unroll
            for (int j = 0; j < 4; ++j) {
                if (gcol < nC) Cz[(size_t)(rbase + j) * ldc + gcol] = v[j];
            }
        }
    }
}

// fp32 -> fp16 (hi only)
__global__ void conv_kernel(const float* __restrict__ src, _Float16* __restrict__ hi, int n4)
{
    for (int i = blockIdx.x * 256 + threadIdx.x; i < n4; i += gridDim.x * 256) {
        f32x4 v = ((const f32x4*)src)[i];
        h4 h;
        #pragma unroll
        for (int j = 0; j < 4; ++j) h[j] = (_Float16)v[j];
        ((h4*)hi)[i] = h;
    }
}

// fp32 -> fp16 hi/lo split (lo scaled x2048)
__global__ void split_kernel(const float* __restrict__ src,
                             _Float16* __restrict__ hi, _Float16* __restrict__ lo, int n4)
{
    for (int i = blockIdx.x * 256 + threadIdx.x; i < n4; i += gridDim.x * 256) {
        f32x4 v = ((const f32x4*)src)[i];
        h4 h, l;
        #pragma unroll
        for (int j = 0; j < 4; ++j) {
            _Float16 hh = (_Float16)v[j];
            h[j] = hh;
            l[j] = (_Float16)((v[j] - (float)hh) * 2048.0f);
        }
        ((h4*)hi)[i] = h;
        ((h4*)lo)[i] = l;
    }
}

// fp32 [nrows,1024] -> fp16 hi(/lo) padded to [1024,1024]
template <bool LO>
__global__ void padsplit_kernel(const float* __restrict__ src,
                                _Float16* __restrict__ hi, _Float16* __restrict__ lo, int nrows)
{
    for (int i = blockIdx.x * 256 + threadIdx.x; i < 1024 * 256; i += gridDim.x * 256) {
        int r = i >> 8;
        f32x4 v = {0.f, 0.f, 0.f, 0.f};
        if (r < nrows) v = ((const f32x4*)src)[i];
        h4 h, l;
        #pragma unroll
        for (int j = 0; j < 4; ++j) {
            _Float16 hh = (_Float16)v[j];
            h[j] = hh;
            if constexpr (LO) l[j] = (_Float16)((v[j] - (float)hh) * 2048.0f);
        }
        ((h4*)hi)[i] = h;
        if constexpr (LO) ((h4*)lo)[i] = l;
    }
}

// cT[n][k] = k<1000 ? fp16(centroid[k][n]) : 0
__global__ __launch_bounds__(256) void ctrans_kernel(const float* __restrict__ centroid,
                                                     _Float16* __restrict__ cT)
{
    __shared__ float tile[32][33];
    const int t = threadIdx.x;
    const int tx = t & 31, ty = t >> 5;
    const int k0 = blockIdx.y * 32, n0 = blockIdx.x * 32;
    #pragma unroll
    for (int p = 0; p < 4; ++p) {
        int k = k0 + ty + p * 8;
        tile[ty + p * 8][tx] = (k < 1000) ? centroid[(size_t)k * 1024 + n0 + tx] : 0.0f;
    }
    __syncthreads();
    #pragma unroll
    for (int p = 0; p < 4; ++p) {
        int n = n0 + ty + p * 8;
        cT[(size_t)n * 1024 + k0 + tx] = (_Float16)tile[tx][ty + p * 8];
    }
}

// shared device body: masked softmax given logits x (len 1000) -> fp16 row y
__device__ __forceinline__ void masked_softmax_body(
    const float* __restrict__ x, _Float16* __restrict__ y,
    int t, float* wv, int* wi, bool flag, int* d_idx, int* d_cnt, int rowid)
{
    float bv = -1e30f, sv = -1e30f; int bi = 0;
    for (int c = t; c < 1000; c += 256) {
        float v = x[c];
        if (v > bv) { sv = bv; bv = v; bi = c; }
        else if (v > sv) sv = v;
    }
    #pragma unroll
    for (int off = 32; off > 0; off >>= 1) {
        float ov = __shfl_down(bv, off, 64);
        int   oi = __shfl_down(bi, off, 64);
        float os = __shfl_down(sv, off, 64);
        if (ov > bv || (ov == bv && oi < bi)) {
            sv = fmaxf(bv, os); bv = ov; bi = oi;
        } else {
            sv = fmaxf(sv, fmaxf(ov, os) == ov ? ov : os);
            sv = fmaxf(sv, ov); sv = fmaxf(sv, os);
        }
    }
    __shared__ float svv[4];
    const int lane = t & 63, wid = t >> 6;
    if (lane == 0) { wv[wid] = bv; wi[wid] = bi; svv[wid] = sv; }
    __syncthreads();
    __shared__ float s_m, s_tot; __shared__ int s_p;
    if (t == 0) {
        float mv = wv[0]; int mi = wi[0]; float m2 = svv[0];
        for (int w = 1; w < 4; ++w) {
            if (wv[w] > mv || (wv[w] == mv && wi[w] < mi)) {
                m2 = fmaxf(mv, svv[w]); mv = wv[w]; mi = wi[w];
            } else {
                m2 = fmaxf(m2, fmaxf(wv[w], svv[w]));
            }
        }
        s_p = mi; s_m = mv;
        if (flag && (mv - m2) < TAU) {
            int slot = atomicAdd(d_cnt, 1);
            if (slot < CAP) d_idx[slot] = rowid;
        }
    }
    __syncthreads();
    const int p = s_p; const float m = s_m;
    if (p >= 500) {
        for (int c = t; c < 1024; c += 256) y[c] = (c == p) ? (_Float16)1.0f : (_Float16)0.0f;
    } else {
        float s = 0.f;
        for (int c = t; c < 1000; c += 256)
            if (c == p || c >= 500) s += expf(x[c] - m);
        #pragma unroll
        for (int off = 32; off > 0; off >>= 1) s += __shfl_down(s, off, 64);
        if (lane == 0) wv[wid] = s;
        __syncthreads();
        if (t == 0) s_tot = wv[0] + wv[1] + wv[2] + wv[3];
        __syncthreads();
        const float inv = 1.0f / s_tot;
        for (int c = t; c < 1024; c += 256) {
            float v = 0.f;
            if (c < 1000 && (c == p || c >= 500)) v = expf(x[c] - m) * inv;
            y[c] = (_Float16)v;
        }
    }
}

__global__ __launch_bounds__(256) void masksm_kernel(const float* __restrict__ o1,
                                                     _Float16* __restrict__ sm,
                                                     int* __restrict__ d_idx,
                                                     int* __restrict__ d_cnt)
{
    __shared__ float wv[4]; __shared__ int wi[4];
    const int row = blockIdx.x;
    masked_softmax_body(o1 + (size_t)row * 1000, sm + (size_t)row * 1024,
                        threadIdx.x, wv, wi, true, d_idx, d_cnt, row);
}

// fixup: sum P2 halves inline (red2 fused), then precise masked softmax rewrite
__global__ __launch_bounds__(256) void fixup_kernel(const float* __restrict__ P2,
                                                    _Float16* __restrict__ sm,
                                                    const int* __restrict__ d_idx,
                                                    const int* __restrict__ d_cnt)
{
    const int slot = blockIdx.x;
    if (slot >= *d_cnt || slot >= CAP) return;
    const int row = d_idx[slot];
    const int t = threadIdx.x;
    __shared__ float xr[1000];
    for (int c = t; c < 1000; c += 256) {
        const size_t o = (size_t)slot * 1000 + c;
        xr[c] = P2[o] + P2[o + (size_t)CAP * 1000];
    }
    __syncthreads();
    __shared__ float wv[4]; __shared__ int wi[4];
    masked_softmax_body(xr, sm + (size_t)row * 1024,
                        t, wv, wi, false, nullptr, nullptr, 0);
}

// gather flagged feature rows -> fp16 hi/lo split [CAP x 2048]
__global__ __launch_bounds__(256) void gather_split_kernel(
    const float* __restrict__ features,
    _Float16* __restrict__ fgh, _Float16* __restrict__ fgl,
    const int* __restrict__ d_idx, const int* __restrict__ d_cnt)
{
    const int slot = blockIdx.x;
    if (slot >= *d_cnt || slot >= CAP) return;
    const int row = d_idx[slot];
    const int t = threadIdx.x;
    #pragma unroll
    for (int q = 0; q < 2; ++q) {
        int o = t * 8 + q * 4;
        f32x4 v = *(const f32x4*)(features + (size_t)row * 2048 + o);
        h4 h, l;
        #pragma unroll
        for (int j = 0; j < 4; ++j) {
            _Float16 hh = (_Float16)v[j];
            h[j] = hh;
            l[j] = (_Float16)((v[j] - (float)hh) * 2048.0f);
        }
        *(h4*)(fgh + (size_t)slot * 2048 + o) = h;
        *(h4*)(fgl + (size_t)slot * 2048 + o) = l;
    }
}

// red1: fgs = split( sum_z P1[z] + bias )
__global__ __launch_bounds__(256) void red1_kernel(const float* __restrict__ P1,
                                                   const float* __restrict__ bias,
                                                   _Float16* __restrict__ fgsh,
                                                   _Float16* __restrict__ fgsl,
                                                   const int* __restrict__ d_cnt)
{
    const int slot = blockIdx.x;
    if (slot >= *d_cnt || slot >= CAP) return;
    const int t = threadIdx.x;
    #pragma unroll
    for (int q = 0; q < 4; ++q) {
        const int c = t + q * 256;
        const size_t o = (size_t)slot * 1024 + c;
        float s = P1[o] + P1[o + (size_t)CAP * 1024] + P1[o + (size_t)2 * CAP * 1024]
                + P1[o + (size_t)3 * CAP * 1024] + bias[c];
        _Float16 h = (_Float16)s;
        fgsh[o] = h;
        fgsl[o] = (_Float16)((s - (float)h) * 2048.0f);
    }
}

// fused: invn = 1/max(||aug_row||,eps); xh = fp16(aug * invn)
__global__ __launch_bounds__(256) void rownorm_x_kernel(const float* __restrict__ aug,
                                                        _Float16* __restrict__ xh)
{
    const int row = blockIdx.x; const int t = threadIdx.x;
    f32x4 v = *((const f32x4*)(aug + (size_t)row * 1024) + t);
    float s = v[0]*v[0] + v[1]*v[1] + v[2]*v[2] + v[3]*v[3];
    #pragma unroll
    for (int off = 32; off > 0; off >>= 1) s += __shfl_down(s, off, 64);
    __shared__ float ws4[4]; __shared__ float s_inv;
    const int lane = t & 63, wid = t >> 6;
    if (lane == 0) ws4[wid] = s;
    __syncthreads();
    if (t == 0) {
        float tot = ws4[0] + ws4[1] + ws4[2] + ws4[3];
        s_inv = 1.0f / fmaxf(sqrtf(tot), 1e-12f);
    }
    __syncthreads();
    const float inv = s_inv;
    h4 h;
    #pragma unroll
    for (int j = 0; j < 4; ++j) h[j] = (_Float16)(v[j] * inv);
    *((h4*)(xh + (size_t)row * 1024) + t) = h;
}

// plain row softmax over 1000
__global__ __launch_bounds__(256) void softmax2_kernel(const float* __restrict__ o2,
                                                       float* __restrict__ out)
{
    const int row = blockIdx.x; const int t = threadIdx.x;
    const float* x = o2 + (size_t)row * 1000;
    float* y = out + (size_t)row * 1000;
    float m = -1e30f;
    for (int c = t; c < 1000; c += 256) m = fmaxf(m, x[c]);
    #pragma unroll
    for (int off = 32; off > 0; off >>= 1) m = fmaxf(m, __shfl_down(m, off, 64));
    __shared__ float sm4[4]; __shared__ float s_m, s_s;
    const int lane = t & 63, wid = t >> 6;
    if (lane == 0) sm4[wid] = m;
    __syncthreads();
    if (t == 0) s_m = fmaxf(fmaxf(sm4[0], sm4[1]), fmaxf(sm4[2], sm4[3]));
    __syncthreads();
    m = s_m;
    float s = 0.f;
    for (int c = t; c < 1000; c += 256) s += expf(x[c] - m);
    #pragma unroll
    for (int off = 32; off > 0; off >>= 1) s += __shfl_down(s, off, 64);
    if (lane == 0) sm4[wid] = s;
    __syncthreads();
    if (t == 0) s_s = sm4[0] + sm4[1] + sm4[2] + sm4[3];
    __syncthreads();
    const float inv = 1.0f / s_s;
    for (int c = t; c < 1000; c += 256) y[c] = expf(x[c] - m) * inv;
}

extern "C" void kernel_launch(void* const* d_in, const int* in_sizes, int n_in,
                              void* d_out, int out_size, void* d_ws, size_t ws_size,
                              hipStream_t stream)
{
    const float* features = (const float*)d_in[0];  // [8192,2048]
    const float* W_b      = (const float*)d_in[1];  // [1024,2048]
    const float* b_b      = (const float*)d_in[2];  // [1024]
    const float* W1       = (const float*)d_in[3];  // [1000,1024]
    const float* W2       = (const float*)d_in[4];  // [1000,1024]
    const float* centroid = (const float*)d_in[5];  // [1000,1024]

    char* base = (char*)d_out;
    float* feats = (float*)(base);
    float* aug   = (float*)(base + 33554432);
    float* o1    = (float*)(base + 67108864);
    float* o2    = (float*)(base + 99876864);
    float* smx   = (float*)(base + 132644864);

    _Float16* fh    = (_Float16*)(base + 67108864);
    _Float16* fetsh = (_Float16*)(base + 33554432);
    float*    P1    = (float*)   (base + 33554432);
    float*    P2    = (float*)   (base + 33554432);
    int*      idx   = (int*)     (base + 50331648);
    int*      cnt   = (int*)     (base + 50339840);
    _Float16* fgsh  = (_Float16*)(base + 50348032);
    _Float16* fgsl  = (_Float16*)(base + 52445184);
    _Float16* sm1h  = (_Float16*)(base + 99876864);
    _Float16* cth   = (_Float16*)(base + 116654080);
    _Float16* wbh   = (_Float16*)(base + 118751232);
    _Float16* wbl   = (_Float16*)(base + 122945536);
    _Float16* w2h   = (_Float16*)(base + 132644864);
    _Float16* w1h   = (_Float16*)(base + 142606336);
    _Float16* w1l   = (_Float16*)(base + 144703488);
    _Float16* fgh   = (_Float16*)(base + 146800640);
    _Float16* fgl   = (_Float16*)(base + 150994944);
    _Float16* xh    = (_Float16*)(base + 146800640);

    zero_cnt_kernel<<<1, 1, 0, stream>>>(cnt);

    // conversions
    conv_kernel<<<2048, 256, 0, stream>>>(features, fh, 4194304);
    split_kernel<<<1024, 256, 0, stream>>>(W_b, wbh, wbl, 524288);
    padsplit_kernel<true><<<1024, 256, 0, stream>>>(W1, w1h, w1l, 1000);
    ctrans_kernel<<<dim3(32, 32), 256, 0, stream>>>(centroid, cth);
    padsplit_kernel<false><<<1024, 256, 0, stream>>>(W2, w2h, nullptr, 1000);

    // G1: feats = F@W_b^T + b_b (fp16x1, 8-phase); epilogue also emits fetsh
    gemm8p<1><<<256, 512, 0, stream>>>(fh, 2048, wbh, 2048, 2048,
                                       feats, 1024, 1024, b_b, fetsh);
    // G2: o1 = feats@W1^T (fp16x1, 8-phase)
    gemm8p<2><<<256, 512, 0, stream>>>(fetsh, 1024, w1h, 1024, 1024,
                                       o1, 1000, 1000, nullptr, nullptr);
    // masked softmax + ambiguity flagging
    masksm_kernel<<<8192, 256, 0, stream>>>(o1, sm1h, idx, cnt);

    // correction chain (flagged rows only; blocks early-exit on cnt)
    gather_split_kernel<<<CAP, 256, 0, stream>>>(features, fgh, fgl, idx, cnt);
    gemmc<<<dim3(8, CAP / 128, 4), 256, 0, stream>>>(fgh, fgl, 2048, wbh, wbl, 2048, 512,
                                                     P1, 1024, 1024, cnt);
    red1_kernel<<<CAP, 256, 0, stream>>>(P1, b_b, fgsh, fgsl, cnt);
    gemmc<<<dim3(8, CAP / 128, 2), 256, 0, stream>>>(fgsh, fgsl, 1024, w1h, w1l, 1024, 512,
                                                     P2, 1000, 1000, cnt);
    fixup_kernel<<<CAP, 256, 0, stream>>>(P2, sm1h, idx, cnt);

    // G3: aug = sm1@centroid + feats (fp16x1, 8-phase)
    gemm8p<3><<<256, 512, 0, stream>>>(sm1h, 1024, cth, 1024, 1024,
                                       aug, 1024, 1024, feats, nullptr);
    rownorm_x_kernel<<<8192, 256, 0, stream>>>(aug, xh);
    // G4: o2 = x@W2^T * 20 (fp16x1, 8-phase)
    gemm8p<4><<<256, 512, 0, stream>>>(xh, 1024, w2h, 1024, 1024,
                                       o2, 1000, 1000, nullptr, nullptr);
    softmax2_kernel<<<8192, 256, 0, stream>>>(o2, smx);
}

// Round 8
// 288.328 us; speedup vs baseline: 1.0817x; 1.0817x over previous
//
#include <hip/hip_runtime.h>
#include <cmath>

// ---------------------------------------------------------------------------
// Classifier pipeline, round 8: launch-count compaction (19 -> 12).
// Main GEMMs: fp16x1 m97 structure (R6 proven). Argmax protected by fp16x2
// correction chain on flagged rows (top-2 gap < TAU), K-split partials.
// prep_kernel fuses all conversions + cnt=0; masksm fuses the feature-gather.
//
// d_out byte layout (total 165,412,864 B):
//   feats [8192,1024] f32 @ 0
//   aug   [8192,1024] f32 @ 33,554,432
//   o1    [8192,1000] f32 @ 67,108,864
//   o2    [8192,1000] f32 @ 99,876,864
//   smx   [8192,1000] f32 @ 132,644,864
//
// Scratch (dead-region hosted; lifetime [first-write .. last-read]):
//   fh    fp16[8192*2048] @  67,108,864  [prep .. G1]        (o1 slot)
//   fetsh fp16[8192*1024] @  33,554,432  [G1 .. G2]          (aug slot)
//   P1    f32[4*1024*1024]@  33,554,432  [gG1 .. red1]       (aug slot, fetsh dead)
//   P2    f32[2*1024*1000]@  33,554,432  [gG2 .. fixup]      (aug slot, P1 dead)
//   idx   int[1024]       @  50,331,648  [masksm .. fixup]
//   cnt   int             @  50,339,840  [prep .. fixup]
//   fgsh  fp16[1024*1024] @  50,348,032  [red1 .. gG2]
//   fgsl  fp16[1024*1024] @  52,445,184  [red1 .. gG2]
//   sm1h  fp16[8192*1024] @  99,876,864  [masksm .. G3]      (o2 slot)
//   cth   fp16[1024*1024] @ 116,654,080  [prep .. G3]
//   wbh   fp16[1024*2048] @ 118,751,232  [prep .. gG1]
//   wbl   fp16[1024*2048] @ 122,945,536  [prep .. gG1]
//   w2h   fp16[1024*1024] @ 132,644,864  [prep .. G4]        (smx slot)
//   w1h   fp16[1024*1024] @ 142,606,336  [prep .. gG2]
//   w1l   fp16[1024*1024] @ 144,703,488  [prep .. gG2]
//   fgh   fp16[1024*2048] @ 146,800,640  [masksm .. gG1]
//   fgl   fp16[1024*2048] @ 150,994,944  [masksm .. gG1]
//   xh    fp16[8192*1024] @ 146,800,640  [rownorm .. G4]     (fgh/fgl dead)
// ---------------------------------------------------------------------------

typedef _Float16 h8 __attribute__((ext_vector_type(8)));
typedef _Float16 h4 __attribute__((ext_vector_type(4)));
typedef float f32x4 __attribute__((ext_vector_type(4)));

#define TAU 0.010f
#define CAP 1024

__device__ __forceinline__ void gload_lds16(const _Float16* g, _Float16* l) {
    __builtin_amdgcn_global_load_lds(
        (const __attribute__((address_space(1))) void*)g,
        (__attribute__((address_space(3))) void*)l, 16, 0, 0);
}

__device__ __forceinline__ void split4(f32x4 v, h4& h, h4& l) {
    #pragma unroll
    for (int j = 0; j < 4; ++j) {
        _Float16 hh = (_Float16)v[j];
        h[j] = hh;
        l[j] = (_Float16)((v[j] - (float)hh) * 2048.0f);
    }
}

// ===========================================================================
// prep: cnt=0 + conv(features) + split(W_b) + padsplit(W1) + ctrans + pad(W2)
// grid sections: [0,2048) conv | [2048,3072) Wb | [3072,4096) W1
//                [4096,5120) ctrans | [5120,6144) W2
// ===========================================================================
__global__ __launch_bounds__(256) void prep_kernel(
    const float* __restrict__ features, _Float16* __restrict__ fh,
    const float* __restrict__ W_b, _Float16* __restrict__ wbh, _Float16* __restrict__ wbl,
    const float* __restrict__ W1, _Float16* __restrict__ w1h, _Float16* __restrict__ w1l,
    const float* __restrict__ W2, _Float16* __restrict__ w2h,
    const float* __restrict__ centroid, _Float16* __restrict__ cth,
    int* __restrict__ cnt)
{
    __shared__ float tile[32][33];
    const int bid = blockIdx.x;
    const int t = threadIdx.x;
    if (bid == 0 && t == 0) *cnt = 0;

    if (bid < 2048) {
        for (int i = bid * 256 + t; i < 4194304; i += 2048 * 256) {
            f32x4 v = ((const f32x4*)features)[i];
            h4 h;
            #pragma unroll
            for (int j = 0; j < 4; ++j) h[j] = (_Float16)v[j];
            ((h4*)fh)[i] = h;
        }
    } else if (bid < 3072) {
        const int i = (bid - 2048) * 512 + t;          // 524,288 f32x4 items
        #pragma unroll
        for (int q = 0; q < 2; ++q) {
            const int k = i + q * 256;
            f32x4 v = ((const f32x4*)W_b)[k];
            h4 h, l; split4(v, h, l);
            ((h4*)wbh)[k] = h;
            ((h4*)wbl)[k] = l;
        }
    } else if (bid < 4096) {
        const int i = (bid - 3072) * 256 + t;          // 262,144 items over [1024,1024]
        const int r = i >> 8;
        f32x4 v = {0.f, 0.f, 0.f, 0.f};
        if (r < 1000) v = ((const f32x4*)W1)[i];
        h4 h, l; split4(v, h, l);
        ((h4*)w1h)[i] = h;
        ((h4*)w1l)[i] = l;
    } else if (bid < 5120) {
        const int local = bid - 4096;
        const int n0 = (local & 31) * 32, k0 = (local >> 5) * 32;
        const int tx = t & 31, ty = t >> 5;
        #pragma unroll
        for (int p = 0; p < 4; ++p) {
            int k = k0 + ty + p * 8;
            tile[ty + p * 8][tx] = (k < 1000) ? centroid[(size_t)k * 1024 + n0 + tx] : 0.0f;
        }
        __syncthreads();
        #pragma unroll
        for (int p = 0; p < 4; ++p) {
            int n = n0 + ty + p * 8;
            cth[(size_t)n * 1024 + k0 + tx] = (_Float16)tile[tx][ty + p * 8];
        }
    } else {
        const int i = (bid - 5120) * 256 + t;          // 262,144 items over [1024,1024]
        const int r = i >> 8;
        f32x4 v = {0.f, 0.f, 0.f, 0.f};
        if (r < 1000) v = ((const f32x4*)W2)[i];
        h4 h;
        #pragma unroll
        for (int j = 0; j < 4; ++j) h[j] = (_Float16)v[j];
        ((h4*)w2h)[i] = h;
    }
}

// ===========================================================================
// Main GEMM (m97 structure, fp16x1), 128x128 tile, 4 waves, gload_lds.
// MODE 1: C = A@B^T + bias(aux); also Ch = fp16(C)
// MODE 2: C = A@B^T, cols<nC
// MODE 3: C = A@B^T + aux[row,col]
// MODE 4: C = A@B^T * 20, cols<nC
// ===========================================================================
template <int MODE>
__global__ __launch_bounds__(256, 4) void gemm16(
    const _Float16* __restrict__ Ah, int lda,
    const _Float16* __restrict__ Bh, int ldb, int K,
    float* __restrict__ C, int ldc, int nC,
    const float* __restrict__ aux, _Float16* __restrict__ Ch)
{
    __shared__ _Float16 sAh[128 * 64];
    __shared__ _Float16 sBh[128 * 64];

    const int t = threadIdx.x;
    const int lane = t & 63, wid = t >> 6;
    // bijective XCD swizzle (512 wgs, 64/XCD -> 8 row-panels x 8 col)
    const int wg = blockIdx.x;
    const int wgid = (wg & 7) * 64 + (wg >> 3);
    const int row0 = (wgid >> 3) * 128, col0 = (wgid & 7) * 128;
    const int wr = wid >> 1, wc = wid & 1;
    const int fr = lane & 15;
    const int fk = (lane >> 4) * 8;
    const int srow = lane >> 3;
    const int scol = (lane & 7) * 8;

    f32x4 acc[4][4] = {};

    for (int k0 = 0; k0 < K; k0 += 64) {
        #pragma unroll
        for (int j = 0; j < 4; ++j) {
            int i = wid * 4 + j;
            int r = i * 8 + srow;
            gload_lds16(Ah + (size_t)(row0 + r) * lda + k0 + scol, &sAh[i * 512]);
            gload_lds16(Bh + (size_t)(col0 + r) * ldb + k0 + scol, &sBh[i * 512]);
        }
        __syncthreads();
        #pragma unroll
        for (int ks = 0; ks < 2; ++ks) {
            h8 ah[4];
            #pragma unroll
            for (int mf = 0; mf < 4; ++mf)
                ah[mf] = *(const h8*)&sAh[(wr * 64 + mf * 16 + fr) * 64 + ks * 32 + fk];
            #pragma unroll
            for (int nf = 0; nf < 4; ++nf) {
                h8 bh = *(const h8*)&sBh[(wc * 64 + nf * 16 + fr) * 64 + ks * 32 + fk];
                #pragma unroll
                for (int mf = 0; mf < 4; ++mf)
                    acc[mf][nf] = __builtin_amdgcn_mfma_f32_16x16x32_f16(ah[mf], bh, acc[mf][nf], 0, 0, 0);
            }
        }
        __syncthreads();
    }
    #pragma unroll
    for (int mf = 0; mf < 4; ++mf) {
        #pragma unroll
        for (int nf = 0; nf < 4; ++nf) {
            f32x4 v = acc[mf][nf];
            const int gcol = col0 + wc * 64 + nf * 16 + fr;
            const int rbase = row0 + wr * 64 + mf * 16 + (lane >> 4) * 4;
            #pragma unroll
            for (int j = 0; j < 4; ++j) {
                const int grow = rbase + j;
                float val = v[j];
                if constexpr (MODE == 1) val += aux[gcol];
                if constexpr (MODE == 3) val += aux[(size_t)grow * 1024 + gcol];
                if constexpr (MODE == 4) val *= 20.0f;
                if (gcol < nC) {
                    C[(size_t)grow * ldc + gcol] = val;
                    if constexpr (MODE == 1)
                        Ch[(size_t)grow * 1024 + gcol] = (_Float16)val;
                }
            }
        }
    }
}

// ===========================================================================
// Chain GEMM (m97, fp16x2, K-split partials via blockIdx.z, early-exit)
// ===========================================================================
__global__ __launch_bounds__(256, 2) void gemmc(
    const _Float16* __restrict__ Ah, const _Float16* __restrict__ Al, int lda,
    const _Float16* __restrict__ Bh, const _Float16* __restrict__ Bl, int ldb,
    int klen,
    float* __restrict__ C, int ldc, int nC,
    const int* __restrict__ cnt)
{
    __shared__ _Float16 sAh[128 * 64];
    __shared__ _Float16 sBh[128 * 64];
    __shared__ _Float16 sAl[128 * 64];
    __shared__ _Float16 sBl[128 * 64];

    const int t = threadIdx.x;
    const int lane = t & 63, wid = t >> 6;
    const int row0 = blockIdx.y * 128, col0 = blockIdx.x * 128;
    const int kbase = blockIdx.z * klen;
    if (row0 >= *cnt) return;
    const int wr = wid >> 1, wc = wid & 1;
    const int fr = lane & 15;
    const int fk = (lane >> 4) * 8;
    const int srow = lane >> 3;
    const int scol = (lane & 7) * 8;

    f32x4 acc[4][4] = {};
    f32x4 accc[4][4] = {};

    for (int k0 = kbase; k0 < kbase + klen; k0 += 64) {
        #pragma unroll
        for (int j = 0; j < 4; ++j) {
            int i = wid * 4 + j;
            int r = i * 8 + srow;
            const size_t ga = (size_t)(row0 + r) * lda + k0 + scol;
            const size_t gb = (size_t)(col0 + r) * ldb + k0 + scol;
            gload_lds16(Ah + ga, &sAh[i * 512]);
            gload_lds16(Bh + gb, &sBh[i * 512]);
            gload_lds16(Al + ga, &sAl[i * 512]);
            gload_lds16(Bl + gb, &sBl[i * 512]);
        }
        __syncthreads();
        #pragma unroll
        for (int ks = 0; ks < 2; ++ks) {
            h8 ah[4], al[4];
            #pragma unroll
            for (int mf = 0; mf < 4; ++mf) {
                int rr = wr * 64 + mf * 16 + fr;
                ah[mf] = *(const h8*)&sAh[rr * 64 + ks * 32 + fk];
                al[mf] = *(const h8*)&sAl[rr * 64 + ks * 32 + fk];
            }
            #pragma unroll
            for (int nf = 0; nf < 4; ++nf) {
                int cc = wc * 64 + nf * 16 + fr;
                h8 bh = *(const h8*)&sBh[cc * 64 + ks * 32 + fk];
                h8 bl = *(const h8*)&sBl[cc * 64 + ks * 32 + fk];
                #pragma unroll
                for (int mf = 0; mf < 4; ++mf) {
                    acc[mf][nf]  = __builtin_amdgcn_mfma_f32_16x16x32_f16(ah[mf], bh, acc[mf][nf], 0, 0, 0);
                    accc[mf][nf] = __builtin_amdgcn_mfma_f32_16x16x32_f16(ah[mf], bl, accc[mf][nf], 0, 0, 0);
                    accc[mf][nf] = __builtin_amdgcn_mfma_f32_16x16x32_f16(al[mf], bh, accc[mf][nf], 0, 0, 0);
                }
            }
        }
        __syncthreads();
    }
    float* Cz = C + (size_t)blockIdx.z * CAP * ldc;
    #pragma unroll
    for (int mf = 0; mf < 4; ++mf) {
        #pragma unroll
        for (int nf = 0; nf < 4; ++nf) {
            f32x4 v = acc[mf][nf] + accc[mf][nf] * (1.0f / 2048.0f);
            const int gcol = col0 + wc * 64 + nf * 16 + fr;
            const int rbase = row0 + wr * 64 + mf * 16 + (lane >> 4) * 4;
            #pragma unroll
            for (int j = 0; j < 4; ++j) {
                if (gcol < nC) Cz[(size_t)(rbase + j) * ldc + gcol] = v[j];
            }
        }
    }
}

// shared device body: masked softmax given logits x (len 1000) -> fp16 row y
// s_slot (shared): correction slot if this row was flagged, else -1
__device__ __forceinline__ void masked_softmax_body(
    const float* __restrict__ x, _Float16* __restrict__ y,
    int t, float* wv, int* wi, bool flag, int* d_idx, int* d_cnt, int rowid,
    int* s_slot)
{
    float bv = -1e30f, sv = -1e30f; int bi = 0;
    for (int c = t; c < 1000; c += 256) {
        float v = x[c];
        if (v > bv) { sv = bv; bv = v; bi = c; }
        else if (v > sv) sv = v;
    }
    #pragma unroll
    for (int off = 32; off > 0; off >>= 1) {
        float ov = __shfl_down(bv, off, 64);
        int   oi = __shfl_down(bi, off, 64);
        float os = __shfl_down(sv, off, 64);
        if (ov > bv || (ov == bv && oi < bi)) {
            sv = fmaxf(bv, os); bv = ov; bi = oi;
        } else {
            sv = fmaxf(sv, fmaxf(ov, os) == ov ? ov : os);
            sv = fmaxf(sv, ov); sv = fmaxf(sv, os);
        }
    }
    __shared__ float svv[4];
    const int lane = t & 63, wid = t >> 6;
    if (lane == 0) { wv[wid] = bv; wi[wid] = bi; svv[wid] = sv; }
    __syncthreads();
    __shared__ float s_m, s_tot; __shared__ int s_p;
    if (t == 0) {
        float mv = wv[0]; int mi = wi[0]; float m2 = svv[0];
        for (int w = 1; w < 4; ++w) {
            if (wv[w] > mv || (wv[w] == mv && wi[w] < mi)) {
                m2 = fmaxf(mv, svv[w]); mv = wv[w]; mi = wi[w];
            } else {
                m2 = fmaxf(m2, fmaxf(wv[w], svv[w]));
            }
        }
        s_p = mi; s_m = mv;
        int slot = -1;
        if (flag && (mv - m2) < TAU) {
            int q = atomicAdd(d_cnt, 1);
            if (q < CAP) { d_idx[q] = rowid; slot = q; }
        }
        *s_slot = slot;
    }
    __syncthreads();
    const int p = s_p; const float m = s_m;
    if (p >= 500) {
        for (int c = t; c < 1024; c += 256) y[c] = (c == p) ? (_Float16)1.0f : (_Float16)0.0f;
    } else {
        float s = 0.f;
        for (int c = t; c < 1000; c += 256)
            if (c == p || c >= 500) s += expf(x[c] - m);
        #pragma unroll
        for (int off = 32; off > 0; off >>= 1) s += __shfl_down(s, off, 64);
        if (lane == 0) wv[wid] = s;
        __syncthreads();
        if (t == 0) s_tot = wv[0] + wv[1] + wv[2] + wv[3];
        __syncthreads();
        const float inv = 1.0f / s_tot;
        for (int c = t; c < 1024; c += 256) {
            float v = 0.f;
            if (c < 1000 && (c == p || c >= 500)) v = expf(x[c] - m) * inv;
            y[c] = (_Float16)v;
        }
    }
}

// masked softmax + ambiguity flagging + fused feature-row gather/split
__global__ __launch_bounds__(256) void masksm_kernel(
    const float* __restrict__ o1, _Float16* __restrict__ sm,
    const float* __restrict__ features,
    _Float16* __restrict__ fgh, _Float16* __restrict__ fgl,
    int* __restrict__ d_idx, int* __restrict__ d_cnt)
{
    __shared__ float wv[4]; __shared__ int wi[4]; __shared__ int s_slot;
    const int row = blockIdx.x;
    const int t = threadIdx.x;
    masked_softmax_body(o1 + (size_t)row * 1000, sm + (size_t)row * 1024,
                        t, wv, wi, true, d_idx, d_cnt, row, &s_slot);
    const int slot = s_slot;                  // visible since mid-body barrier
    if (slot >= 0) {
        #pragma unroll
        for (int q = 0; q < 2; ++q) {
            int o = t * 8 + q * 4;
            f32x4 v = *(const f32x4*)(features + (size_t)row * 2048 + o);
            h4 h, l; split4(v, h, l);
            *(h4*)(fgh + (size_t)slot * 2048 + o) = h;
            *(h4*)(fgl + (size_t)slot * 2048 + o) = l;
        }
    }
}

// fixup: sum P2 halves inline, then precise masked softmax rewrite
__global__ __launch_bounds__(256) void fixup_kernel(const float* __restrict__ P2,
                                                    _Float16* __restrict__ sm,
                                                    const int* __restrict__ d_idx,
                                                    const int* __restrict__ d_cnt)
{
    const int slot = blockIdx.x;
    if (slot >= *d_cnt || slot >= CAP) return;
    const int row = d_idx[slot];
    const int t = threadIdx.x;
    __shared__ float xr[1000];
    for (int c = t; c < 1000; c += 256) {
        const size_t o = (size_t)slot * 1000 + c;
        xr[c] = P2[o] + P2[o + (size_t)CAP * 1000];
    }
    __syncthreads();
    __shared__ float wv[4]; __shared__ int wi[4]; __shared__ int s_slot;
    masked_softmax_body(xr, sm + (size_t)row * 1024,
                        t, wv, wi, false, nullptr, nullptr, 0, &s_slot);
}

// red1: fgs = split( sum_z P1[z] + bias )
__global__ __launch_bounds__(256) void red1_kernel(const float* __restrict__ P1,
                                                   const float* __restrict__ bias,
                                                   _Float16* __restrict__ fgsh,
                                                   _Float16* __restrict__ fgsl,
                                                   const int* __restrict__ d_cnt)
{
    const int slot = blockIdx.x;
    if (slot >= *d_cnt || slot >= CAP) return;
    const int t = threadIdx.x;
    #pragma unroll
    for (int q = 0; q < 4; ++q) {
        const int c = t + q * 256;
        const size_t o = (size_t)slot * 1024 + c;
        float s = P1[o] + P1[o + (size_t)CAP * 1024] + P1[o + (size_t)2 * CAP * 1024]
                + P1[o + (size_t)3 * CAP * 1024] + bias[c];
        _Float16 h = (_Float16)s;
        fgsh[o] = h;
        fgsl[o] = (_Float16)((s - (float)h) * 2048.0f);
    }
}

// fused: invn = 1/max(||aug_row||,eps); xh = fp16(aug * invn)
__global__ __launch_bounds__(256) void rownorm_x_kernel(const float* __restrict__ aug,
                                                        _Float16* __restrict__ xh)
{
    const int row = blockIdx.x; const int t = threadIdx.x;
    f32x4 v = *((const f32x4*)(aug + (size_t)row * 1024) + t);
    float s = v[0]*v[0] + v[1]*v[1] + v[2]*v[2] + v[3]*v[3];
    #pragma unroll
    for (int off = 32; off > 0; off >>= 1) s += __shfl_down(s, off, 64);
    __shared__ float ws4[4]; __shared__ float s_inv;
    const int lane = t & 63, wid = t >> 6;
    if (lane == 0) ws4[wid] = s;
    __syncthreads();
    if (t == 0) {
        float tot = ws4[0] + ws4[1] + ws4[2] + ws4[3];
        s_inv = 1.0f / fmaxf(sqrtf(tot), 1e-12f);
    }
    __syncthreads();
    const float inv = s_inv;
    h4 h;
    #pragma unroll
    for (int j = 0; j < 4; ++j) h[j] = (_Float16)(v[j] * inv);
    *((h4*)(xh + (size_t)row * 1024) + t) = h;
}

// plain row softmax over 1000
__global__ __launch_bounds__(256) void softmax2_kernel(const float* __restrict__ o2,
                                                       float* __restrict__ out)
{
    const int row = blockIdx.x; const int t = threadIdx.x;
    const float* x = o2 + (size_t)row * 1000;
    float* y = out + (size_t)row * 1000;
    float m = -1e30f;
    for (int c = t; c < 1000; c += 256) m = fmaxf(m, x[c]);
    #pragma unroll
    for (int off = 32; off > 0; off >>= 1) m = fmaxf(m, __shfl_down(m, off, 64));
    __shared__ float sm4[4]; __shared__ float s_m, s_s;
    const int lane = t & 63, wid = t >> 6;
    if (lane == 0) sm4[wid] = m;
    __syncthreads();
    if (t == 0) s_m = fmaxf(fmaxf(sm4[0], sm4[1]), fmaxf(sm4[2], sm4[3]));
    __syncthreads();
    m = s_m;
    float s = 0.f;
    for (int c = t; c < 1000; c += 256) s += expf(x[c] - m);
    #pragma unroll
    for (int off = 32; off > 0; off >>= 1) s += __shfl_down(s, off, 64);
    if (lane == 0) sm4[wid] = s;
    __syncthreads();
    if (t == 0) s_s = sm4[0] + sm4[1] + sm4[2] + sm4[3];
    __syncthreads();
    const float inv = 1.0f / s_s;
    for (int c = t; c < 1000; c += 256) y[c] = expf(x[c] - m) * inv;
}

extern "C" void kernel_launch(void* const* d_in, const int* in_sizes, int n_in,
                              void* d_out, int out_size, void* d_ws, size_t ws_size,
                              hipStream_t stream)
{
    const float* features = (const float*)d_in[0];  // [8192,2048]
    const float* W_b      = (const float*)d_in[1];  // [1024,2048]
    const float* b_b      = (const float*)d_in[2];  // [1024]
    const float* W1       = (const float*)d_in[3];  // [1000,1024]
    const float* W2       = (const float*)d_in[4];  // [1000,1024]
    const float* centroid = (const float*)d_in[5];  // [1000,1024]

    char* base = (char*)d_out;
    float* feats = (float*)(base);
    float* aug   = (float*)(base + 33554432);
    float* o1    = (float*)(base + 67108864);
    float* o2    = (float*)(base + 99876864);
    float* smx   = (float*)(base + 132644864);

    _Float16* fh    = (_Float16*)(base + 67108864);
    _Float16* fetsh = (_Float16*)(base + 33554432);
    float*    P1    = (float*)   (base + 33554432);
    float*    P2    = (float*)   (base + 33554432);
    int*      idx   = (int*)     (base + 50331648);
    int*      cnt   = (int*)     (base + 50339840);
    _Float16* fgsh  = (_Float16*)(base + 50348032);
    _Float16* fgsl  = (_Float16*)(base + 52445184);
    _Float16* sm1h  = (_Float16*)(base + 99876864);
    _Float16* cth   = (_Float16*)(base + 116654080);
    _Float16* wbh   = (_Float16*)(base + 118751232);
    _Float16* wbl   = (_Float16*)(base + 122945536);
    _Float16* w2h   = (_Float16*)(base + 132644864);
    _Float16* w1h   = (_Float16*)(base + 142606336);
    _Float16* w1l   = (_Float16*)(base + 144703488);
    _Float16* fgh   = (_Float16*)(base + 146800640);
    _Float16* fgl   = (_Float16*)(base + 150994944);
    _Float16* xh    = (_Float16*)(base + 146800640);

    // 1: all conversions + cnt=0
    prep_kernel<<<6144, 256, 0, stream>>>(features, fh, W_b, wbh, wbl,
                                          W1, w1h, w1l, W2, w2h, centroid, cth, cnt);
    // 2: G1 feats = F@W_b^T + b_b; epilogue also emits fetsh
    gemm16<1><<<512, 256, 0, stream>>>(fh, 2048, wbh, 2048, 2048,
                                       feats, 1024, 1024, b_b, fetsh);
    // 3: G2 o1 = feats@W1^T
    gemm16<2><<<512, 256, 0, stream>>>(fetsh, 1024, w1h, 1024, 1024,
                                       o1, 1000, 1000, nullptr, nullptr);
    // 4: masked softmax + flagging + fused gather
    masksm_kernel<<<8192, 256, 0, stream>>>(o1, sm1h, features, fgh, fgl, idx, cnt);
    // 5-8: correction chain (flagged rows only; blocks early-exit on cnt)
    gemmc<<<dim3(8, CAP / 128, 4), 256, 0, stream>>>(fgh, fgl, 2048, wbh, wbl, 2048, 512,
                                                     P1, 1024, 1024, cnt);
    red1_kernel<<<CAP, 256, 0, stream>>>(P1, b_b, fgsh, fgsl, cnt);
    gemmc<<<dim3(8, CAP / 128, 2), 256, 0, stream>>>(fgsh, fgsl, 1024, w1h, w1l, 1024, 512,
                                                     P2, 1000, 1000, cnt);
    fixup_kernel<<<CAP, 256, 0, stream>>>(P2, sm1h, idx, cnt);
    // 9: G3 aug = sm1@centroid + feats
    gemm16<3><<<512, 256, 0, stream>>>(sm1h, 1024, cth, 1024, 1024,
                                       aug, 1024, 1024, feats, nullptr);
    // 10: rownorm + x conversion
    rownorm_x_kernel<<<8192, 256, 0, stream>>>(aug, xh);
    // 11: G4 o2 = x@W2^T * 20
    gemm16<4><<<512, 256, 0, stream>>>(xh, 1024, w2h, 1024, 1024,
                                       o2, 1000, 1000, nullptr, nullptr);
    // 12: final softmax
    softmax2_kernel<<<8192, 256, 0, stream>>>(o2, smx);
}

// Round 9
// 260.214 us; speedup vs baseline: 1.1986x; 1.1080x over previous
//
#include <hip/hip_runtime.h>
#include <cmath>

// ---------------------------------------------------------------------------
// Classifier pipeline, round 9.
// Main GEMMs: fp16x1 m97 structure. G3 exploits sm1 structure: dense K=512
// (private classes 500..999 compacted) + per-row rank-1 pw*centroid[pidx]
// term in the epilogue (fp32 exact). Argmax protected by fp16x2 correction
// chain on flagged rows (top-2 gap < TAU), K-split partials.
//
// d_out byte layout (total 165,412,864 B):
//   feats [8192,1024] f32 @ 0
//   aug   [8192,1024] f32 @ 33,554,432
//   o1    [8192,1000] f32 @ 67,108,864
//   o2    [8192,1000] f32 @ 99,876,864
//   smx   [8192,1000] f32 @ 132,644,864
//
// Scratch (dead-region hosted; lifetime [first-write .. last-read]):
//   fh    fp16[8192*2048] @  67,108,864  [prep .. G1]        (o1 slot)
//   fetsh fp16[8192*1024] @  33,554,432  [G1 .. G2]          (aug slot)
//   P1    f32[4*1024*1024]@  33,554,432  [gG1 .. red1]       (aug slot, fetsh dead)
//   P2    f32[4*1024*1000]@  33,554,432  [gG2 .. fixup]      (ends 49,938,432)
//   idx   int[1024]       @  50,331,648  [masksm .. fixup]
//   cnt   int             @  50,339,840  [prep .. fixup]
//   fgsh  fp16[1024*1024] @  50,348,032  [red1 .. gG2]
//   fgsl  fp16[1024*1024] @  52,445,184  [red1 .. gG2]
//   sm1c  fp16[8192*512]  @  99,876,864  [masksm .. G3]      (o2 slot)
//   pidx  int[8192]       @ 108,265,472  [masksm .. G3]
//   pw    f32[8192]       @ 108,298,240  [masksm .. G3]
//   cthc  fp16[1024*512]  @ 116,654,080  [prep .. G3]
//   wbh   fp16[1024*2048] @ 118,751,232  [prep .. gG1]
//   wbl   fp16[1024*2048] @ 122,945,536  [prep .. gG1]
//   w2h   fp16[1024*1024] @ 132,644,864  [prep .. G4]        (smx slot)
//   w1h   fp16[1024*1024] @ 142,606,336  [prep .. gG2]
//   w1l   fp16[1024*1024] @ 144,703,488  [prep .. gG2]
//   fgh   fp16[1024*2048] @ 146,800,640  [masksm .. gG1]
//   fgl   fp16[1024*2048] @ 150,994,944  [masksm .. gG1]
//   xh    fp16[8192*1024] @ 146,800,640  [rownorm .. G4]     (fgh/fgl dead)
// ---------------------------------------------------------------------------

typedef _Float16 h8 __attribute__((ext_vector_type(8)));
typedef _Float16 h4 __attribute__((ext_vector_type(4)));
typedef float f32x4 __attribute__((ext_vector_type(4)));

#define TAU 0.010f
#define CAP 1024

__device__ __forceinline__ void gload_lds16(const _Float16* g, _Float16* l) {
    __builtin_amdgcn_global_load_lds(
        (const __attribute__((address_space(1))) void*)g,
        (__attribute__((address_space(3))) void*)l, 16, 0, 0);
}

__device__ __forceinline__ void split4(f32x4 v, h4& h, h4& l) {
    #pragma unroll
    for (int j = 0; j < 4; ++j) {
        _Float16 hh = (_Float16)v[j];
        h[j] = hh;
        l[j] = (_Float16)((v[j] - (float)hh) * 2048.0f);
    }
}

// ===========================================================================
// prep: cnt=0 + conv(features) + split(W_b) + padsplit(W1) + ctransc + pad(W2)
// sections: [0,2048) conv | [2048,3072) Wb | [3072,4096) W1
//           [4096,4608) ctransc (512-K compact) | [4608,5632) W2
// ===========================================================================
__global__ __launch_bounds__(256) void prep_kernel(
    const float* __restrict__ features, _Float16* __restrict__ fh,
    const float* __restrict__ W_b, _Float16* __restrict__ wbh, _Float16* __restrict__ wbl,
    const float* __restrict__ W1, _Float16* __restrict__ w1h, _Float16* __restrict__ w1l,
    const float* __restrict__ W2, _Float16* __restrict__ w2h,
    const float* __restrict__ centroid, _Float16* __restrict__ cthc,
    int* __restrict__ cnt)
{
    __shared__ float tile[32][33];
    const int bid = blockIdx.x;
    const int t = threadIdx.x;
    if (bid == 0 && t == 0) *cnt = 0;

    if (bid < 2048) {
        for (int i = bid * 256 + t; i < 4194304; i += 2048 * 256) {
            f32x4 v = ((const f32x4*)features)[i];
            h4 h;
            #pragma unroll
            for (int j = 0; j < 4; ++j) h[j] = (_Float16)v[j];
            ((h4*)fh)[i] = h;
        }
    } else if (bid < 3072) {
        const int i = (bid - 2048) * 512 + t;
        #pragma unroll
        for (int q = 0; q < 2; ++q) {
            const int k = i + q * 256;
            f32x4 v = ((const f32x4*)W_b)[k];
            h4 h, l; split4(v, h, l);
            ((h4*)wbh)[k] = h;
            ((h4*)wbl)[k] = l;
        }
    } else if (bid < 4096) {
        const int i = (bid - 3072) * 256 + t;
        const int r = i >> 8;
        f32x4 v = {0.f, 0.f, 0.f, 0.f};
        if (r < 1000) v = ((const f32x4*)W1)[i];
        h4 h, l; split4(v, h, l);
        ((h4*)w1h)[i] = h;
        ((h4*)w1l)[i] = l;
    } else if (bid < 4608) {
        // cthc[n][k] = k<500 ? centroid[500+k][n] : 0   (n:1024, k:512)
        const int local = bid - 4096;
        const int n0 = (local & 31) * 32, k0 = (local >> 5) * 32;
        const int tx = t & 31, ty = t >> 5;
        #pragma unroll
        for (int p = 0; p < 4; ++p) {
            int k = k0 + ty + p * 8;
            tile[ty + p * 8][tx] = (k < 500) ? centroid[(size_t)(500 + k) * 1024 + n0 + tx] : 0.0f;
        }
        __syncthreads();
        #pragma unroll
        for (int p = 0; p < 4; ++p) {
            int n = n0 + ty + p * 8;
            cthc[(size_t)n * 512 + k0 + tx] = (_Float16)tile[tx][ty + p * 8];
        }
    } else {
        const int i = (bid - 4608) * 256 + t;
        const int r = i >> 8;
        f32x4 v = {0.f, 0.f, 0.f, 0.f};
        if (r < 1000) v = ((const f32x4*)W2)[i];
        h4 h;
        #pragma unroll
        for (int j = 0; j < 4; ++j) h[j] = (_Float16)v[j];
        ((h4*)w2h)[i] = h;
    }
}

// ===========================================================================
// Main GEMM (m97 structure, fp16x1), 128x128 tile, 4 waves, gload_lds.
// MODE 1: C = A@B^T + bias(aux); also Ch = fp16(C)
// MODE 2: C = A@B^T, cols<nC
// MODE 3: C = A@B^T + aux[row,col] + pw[row]*cent[pidx[row]][col]
// MODE 4: C = A@B^T * 20, cols<nC
// ===========================================================================
template <int MODE>
__global__ __launch_bounds__(256, 4) void gemm16(
    const _Float16* __restrict__ Ah, int lda,
    const _Float16* __restrict__ Bh, int ldb, int K,
    float* __restrict__ C, int ldc, int nC,
    const float* __restrict__ aux, _Float16* __restrict__ Ch,
    const float* __restrict__ cent, const int* __restrict__ pidx,
    const float* __restrict__ pw)
{
    __shared__ _Float16 sAh[128 * 64];
    __shared__ _Float16 sBh[128 * 64];

    const int t = threadIdx.x;
    const int lane = t & 63, wid = t >> 6;
    // bijective XCD swizzle (512 wgs, 64/XCD -> 8 row-panels x 8 col)
    const int wg = blockIdx.x;
    const int wgid = (wg & 7) * 64 + (wg >> 3);
    const int row0 = (wgid >> 3) * 128, col0 = (wgid & 7) * 128;
    const int wr = wid >> 1, wc = wid & 1;
    const int fr = lane & 15;
    const int fk = (lane >> 4) * 8;
    const int srow = lane >> 3;
    const int scol = (lane & 7) * 8;

    f32x4 acc[4][4] = {};

    for (int k0 = 0; k0 < K; k0 += 64) {
        #pragma unroll
        for (int j = 0; j < 4; ++j) {
            int i = wid * 4 + j;
            int r = i * 8 + srow;
            gload_lds16(Ah + (size_t)(row0 + r) * lda + k0 + scol, &sAh[i * 512]);
            gload_lds16(Bh + (size_t)(col0 + r) * ldb + k0 + scol, &sBh[i * 512]);
        }
        __syncthreads();
        #pragma unroll
        for (int ks = 0; ks < 2; ++ks) {
            h8 ah[4];
            #pragma unroll
            for (int mf = 0; mf < 4; ++mf)
                ah[mf] = *(const h8*)&sAh[(wr * 64 + mf * 16 + fr) * 64 + ks * 32 + fk];
            #pragma unroll
            for (int nf = 0; nf < 4; ++nf) {
                h8 bh = *(const h8*)&sBh[(wc * 64 + nf * 16 + fr) * 64 + ks * 32 + fk];
                #pragma unroll
                for (int mf = 0; mf < 4; ++mf)
                    acc[mf][nf] = __builtin_amdgcn_mfma_f32_16x16x32_f16(ah[mf], bh, acc[mf][nf], 0, 0, 0);
            }
        }
        __syncthreads();
    }
    #pragma unroll
    for (int mf = 0; mf < 4; ++mf) {
        #pragma unroll
        for (int nf = 0; nf < 4; ++nf) {
            f32x4 v = acc[mf][nf];
            const int gcol = col0 + wc * 64 + nf * 16 + fr;
            const int rbase = row0 + wr * 64 + mf * 16 + (lane >> 4) * 4;
            #pragma unroll
            for (int j = 0; j < 4; ++j) {
                const int grow = rbase + j;
                float val = v[j];
                if constexpr (MODE == 1) val += aux[gcol];
                if constexpr (MODE == 3) {
                    const int p = pidx[grow];
                    val += aux[(size_t)grow * 1024 + gcol]
                         + pw[grow] * cent[(size_t)p * 1024 + gcol];
                }
                if constexpr (MODE == 4) val *= 20.0f;
                if (gcol < nC) {
                    C[(size_t)grow * ldc + gcol] = val;
                    if constexpr (MODE == 1)
                        Ch[(size_t)grow * 1024 + gcol] = (_Float16)val;
                }
            }
        }
    }
}

// ===========================================================================
// Chain GEMM (m97, fp16x2, K-split partials via blockIdx.z, early-exit)
// ===========================================================================
__global__ __launch_bounds__(256, 2) void gemmc(
    const _Float16* __restrict__ Ah, const _Float16* __restrict__ Al, int lda,
    const _Float16* __restrict__ Bh, const _Float16* __restrict__ Bl, int ldb,
    int klen,
    float* __restrict__ C, int ldc, int nC,
    const int* __restrict__ cnt)
{
    __shared__ _Float16 sAh[128 * 64];
    __shared__ _Float16 sBh[128 * 64];
    __shared__ _Float16 sAl[128 * 64];
    __shared__ _Float16 sBl[128 * 64];

    const int t = threadIdx.x;
    const int lane = t & 63, wid = t >> 6;
    const int row0 = blockIdx.y * 128, col0 = blockIdx.x * 128;
    const int kbase = blockIdx.z * klen;
    if (row0 >= *cnt) return;
    const int wr = wid >> 1, wc = wid & 1;
    const int fr = lane & 15;
    const int fk = (lane >> 4) * 8;
    const int srow = lane >> 3;
    const int scol = (lane & 7) * 8;

    f32x4 acc[4][4] = {};
    f32x4 accc[4][4] = {};

    for (int k0 = kbase; k0 < kbase + klen; k0 += 64) {
        #pragma unroll
        for (int j = 0; j < 4; ++j) {
            int i = wid * 4 + j;
            int r = i * 8 + srow;
            const size_t ga = (size_t)(row0 + r) * lda + k0 + scol;
            const size_t gb = (size_t)(col0 + r) * ldb + k0 + scol;
            gload_lds16(Ah + ga, &sAh[i * 512]);
            gload_lds16(Bh + gb, &sBh[i * 512]);
            gload_lds16(Al + ga, &sAl[i * 512]);
            gload_lds16(Bl + gb, &sBl[i * 512]);
        }
        __syncthreads();
        #pragma unroll
        for (int ks = 0; ks < 2; ++ks) {
            h8 ah[4], al[4];
            #pragma unroll
            for (int mf = 0; mf < 4; ++mf) {
                int rr = wr * 64 + mf * 16 + fr;
                ah[mf] = *(const h8*)&sAh[rr * 64 + ks * 32 + fk];
                al[mf] = *(const h8*)&sAl[rr * 64 + ks * 32 + fk];
            }
            #pragma unroll
            for (int nf = 0; nf < 4; ++nf) {
                int cc = wc * 64 + nf * 16 + fr;
                h8 bh = *(const h8*)&sBh[cc * 64 + ks * 32 + fk];
                h8 bl = *(const h8*)&sBl[cc * 64 + ks * 32 + fk];
                #pragma unroll
                for (int mf = 0; mf < 4; ++mf) {
                    acc[mf][nf]  = __builtin_amdgcn_mfma_f32_16x16x32_f16(ah[mf], bh, acc[mf][nf], 0, 0, 0);
                    accc[mf][nf] = __builtin_amdgcn_mfma_f32_16x16x32_f16(ah[mf], bl, accc[mf][nf], 0, 0, 0);
                    accc[mf][nf] = __builtin_amdgcn_mfma_f32_16x16x32_f16(al[mf], bh, accc[mf][nf], 0, 0, 0);
                }
            }
        }
        __syncthreads();
    }
    float* Cz = C + (size_t)blockIdx.z * CAP * ldc;
    #pragma unroll
    for (int mf = 0; mf < 4; ++mf) {
        #pragma unroll
        for (int nf = 0; nf < 4; ++nf) {
            f32x4 v = acc[mf][nf] + accc[mf][nf] * (1.0f / 2048.0f);
            const int gcol = col0 + wc * 64 + nf * 16 + fr;
            const int rbase = row0 + wr * 64 + mf * 16 + (lane >> 4) * 4;
            #pragma unroll
            for (int j = 0; j < 4; ++j) {
                if (gcol < nC) Cz[(size_t)(rbase + j) * ldc + gcol] = v[j];
            }
        }
    }
}

// shared device body: masked softmax on logits x (len 1000) -> COMPACT outputs:
// y[512] = sm1 over classes 500..999 (zeros if one-hot), pw/pidx rank-1 term.
__device__ __forceinline__ void masked_softmax_body(
    const float* __restrict__ x, _Float16* __restrict__ y,
    float* __restrict__ pwp, int* __restrict__ pidxp,
    int t, float* wv, int* wi, bool flag, int* d_idx, int* d_cnt, int rowid,
    int* s_slot)
{
    float bv = -1e30f, sv = -1e30f; int bi = 0;
    for (int c = t; c < 1000; c += 256) {
        float v = x[c];
        if (v > bv) { sv = bv; bv = v; bi = c; }
        else if (v > sv) sv = v;
    }
    #pragma unroll
    for (int off = 32; off > 0; off >>= 1) {
        float ov = __shfl_down(bv, off, 64);
        int   oi = __shfl_down(bi, off, 64);
        float os = __shfl_down(sv, off, 64);
        if (ov > bv || (ov == bv && oi < bi)) {
            sv = fmaxf(bv, os); bv = ov; bi = oi;
        } else {
            sv = fmaxf(sv, fmaxf(ov, os) == ov ? ov : os);
            sv = fmaxf(sv, ov); sv = fmaxf(sv, os);
        }
    }
    __shared__ float svv[4];
    const int lane = t & 63, wid = t >> 6;
    if (lane == 0) { wv[wid] = bv; wi[wid] = bi; svv[wid] = sv; }
    __syncthreads();
    __shared__ float s_m, s_tot; __shared__ int s_p;
    if (t == 0) {
        float mv = wv[0]; int mi = wi[0]; float m2 = svv[0];
        for (int w = 1; w < 4; ++w) {
            if (wv[w] > mv || (wv[w] == mv && wi[w] < mi)) {
                m2 = fmaxf(mv, svv[w]); mv = wv[w]; mi = wi[w];
            } else {
                m2 = fmaxf(m2, fmaxf(wv[w], svv[w]));
            }
        }
        s_p = mi; s_m = mv;
        int slot = -1;
        if (flag && (mv - m2) < TAU) {
            int q = atomicAdd(d_cnt, 1);
            if (q < CAP) { d_idx[q] = rowid; slot = q; }
        }
        *s_slot = slot;
    }
    __syncthreads();
    const int p = s_p; const float m = s_m;
    if (p >= 500) {
        // one-hot row: dense part zero; rank-1 term = 1.0 * centroid[p]
        for (int c = t; c < 512; c += 256) y[c] = (_Float16)0.0f;
        if (t == 0) { pwp[0] = 1.0f; pidxp[0] = p; }
    } else {
        float s = 0.f;
        for (int c = t; c < 1000; c += 256)
            if (c == p || c >= 500) s += expf(x[c] - m);
        #pragma unroll
        for (int off = 32; off > 0; off >>= 1) s += __shfl_down(s, off, 64);
        if (lane == 0) wv[wid] = s;
        __syncthreads();
        if (t == 0) s_tot = wv[0] + wv[1] + wv[2] + wv[3];
        __syncthreads();
        const float inv = 1.0f / s_tot;
        for (int c = t; c < 512; c += 256) {
            float v = 0.f;
            if (c < 500) v = expf(x[500 + c] - m) * inv;
            y[c] = (_Float16)v;
        }
        if (t == 0) { pwp[0] = inv; pidxp[0] = p; }  // sm1[p] = exp(0)*inv = inv
    }
}

// masked softmax + flagging + fused feature gather; LDS-cached logit row
__global__ __launch_bounds__(256) void masksm_kernel(
    const float* __restrict__ o1, _Float16* __restrict__ sm1c,
    float* __restrict__ pwa, int* __restrict__ pidxa,
    const float* __restrict__ features,
    _Float16* __restrict__ fgh, _Float16* __restrict__ fgl,
    int* __restrict__ d_idx, int* __restrict__ d_cnt)
{
    __shared__ float xs[1000];
    __shared__ float wv[4]; __shared__ int wi[4]; __shared__ int s_slot;
    const int row = blockIdx.x;
    const int t = threadIdx.x;
    const float* x = o1 + (size_t)row * 1000;
    for (int c = t; c < 1000; c += 256) xs[c] = x[c];
    __syncthreads();
    masked_softmax_body(xs, sm1c + (size_t)row * 512, pwa + row, pidxa + row,
                        t, wv, wi, true, d_idx, d_cnt, row, &s_slot);
    const int slot = s_slot;
    if (slot >= 0) {
        #pragma unroll
        for (int q = 0; q < 2; ++q) {
            int o = t * 8 + q * 4;
            f32x4 v = *(const f32x4*)(features + (size_t)row * 2048 + o);
            h4 h, l; split4(v, h, l);
            *(h4*)(fgh + (size_t)slot * 2048 + o) = h;
            *(h4*)(fgl + (size_t)slot * 2048 + o) = l;
        }
    }
}

// fixup: sum 4 P2 partials, then precise masked-softmax rewrite (compact)
__global__ __launch_bounds__(256) void fixup_kernel(
    const float* __restrict__ P2, _Float16* __restrict__ sm1c,
    float* __restrict__ pwa, int* __restrict__ pidxa,
    const int* __restrict__ d_idx, const int* __restrict__ d_cnt)
{
    const int slot = blockIdx.x;
    if (slot >= *d_cnt || slot >= CAP) return;
    const int row = d_idx[slot];
    const int t = threadIdx.x;
    __shared__ float xr[1000];
    for (int c = t; c < 1000; c += 256) {
        const size_t o = (size_t)slot * 1000 + c;
        xr[c] = (P2[o] + P2[o + (size_t)CAP * 1000])
              + (P2[o + (size_t)2 * CAP * 1000] + P2[o + (size_t)3 * CAP * 1000]);
    }
    __syncthreads();
    __shared__ float wv[4]; __shared__ int wi[4]; __shared__ int s_slot;
    masked_softmax_body(xr, sm1c + (size_t)row * 512, pwa + row, pidxa + row,
                        t, wv, wi, false, nullptr, nullptr, 0, &s_slot);
}

// red1: fgs = split( sum_z P1[z] + bias )
__global__ __launch_bounds__(256) void red1_kernel(const float* __restrict__ P1,
                                                   const float* __restrict__ bias,
                                                   _Float16* __restrict__ fgsh,
                                                   _Float16* __restrict__ fgsl,
                                                   const int* __restrict__ d_cnt)
{
    const int slot = blockIdx.x;
    if (slot >= *d_cnt || slot >= CAP) return;
    const int t = threadIdx.x;
    #pragma unroll
    for (int q = 0; q < 4; ++q) {
        const int c = t + q * 256;
        const size_t o = (size_t)slot * 1024 + c;
        float s = P1[o] + P1[o + (size_t)CAP * 1024] + P1[o + (size_t)2 * CAP * 1024]
                + P1[o + (size_t)3 * CAP * 1024] + bias[c];
        _Float16 h = (_Float16)s;
        fgsh[o] = h;
        fgsl[o] = (_Float16)((s - (float)h) * 2048.0f);
    }
}

// fused: invn = 1/max(||aug_row||,eps); xh = fp16(aug * invn)
__global__ __launch_bounds__(256) void rownorm_x_kernel(const float* __restrict__ aug,
                                                        _Float16* __restrict__ xh)
{
    const int row = blockIdx.x; const int t = threadIdx.x;
    f32x4 v = *((const f32x4*)(aug + (size_t)row * 1024) + t);
    float s = v[0]*v[0] + v[1]*v[1] + v[2]*v[2] + v[3]*v[3];
    #pragma unroll
    for (int off = 32; off > 0; off >>= 1) s += __shfl_down(s, off, 64);
    __shared__ float ws4[4]; __shared__ float s_inv;
    const int lane = t & 63, wid = t >> 6;
    if (lane == 0) ws4[wid] = s;
    __syncthreads();
    if (t == 0) {
        float tot = ws4[0] + ws4[1] + ws4[2] + ws4[3];
        s_inv = 1.0f / fmaxf(sqrtf(tot), 1e-12f);
    }
    __syncthreads();
    const float inv = s_inv;
    h4 h;
    #pragma unroll
    for (int j = 0; j < 4; ++j) h[j] = (_Float16)(v[j] * inv);
    *((h4*)(xh + (size_t)row * 1024) + t) = h;
}

// row softmax over 1000, register-resident (4 values/thread, 1 read, 1 expf)
__global__ __launch_bounds__(256) void softmax2_kernel(const float* __restrict__ o2,
                                                       float* __restrict__ out)
{
    const int row = blockIdx.x; const int t = threadIdx.x;
    const float* x = o2 + (size_t)row * 1000;
    float* y = out + (size_t)row * 1000;
    const bool has3 = (t < 232);
    float v0 = x[t], v1 = x[t + 256], v2 = x[t + 512];
    float v3 = has3 ? x[t + 768] : -1e30f;
    float m = fmaxf(fmaxf(v0, v1), fmaxf(v2, v3));
    #pragma unroll
    for (int off = 32; off > 0; off >>= 1) m = fmaxf(m, __shfl_down(m, off, 64));
    __shared__ float sm4[4]; __shared__ float s_m, s_s;
    const int lane = t & 63, wid = t >> 6;
    if (lane == 0) sm4[wid] = m;
    __syncthreads();
    if (t == 0) s_m = fmaxf(fmaxf(sm4[0], sm4[1]), fmaxf(sm4[2], sm4[3]));
    __syncthreads();
    m = s_m;
    float e0 = expf(v0 - m), e1 = expf(v1 - m), e2 = expf(v2 - m);
    float e3 = has3 ? expf(v3 - m) : 0.0f;
    float s = (e0 + e1) + (e2 + e3);
    #pragma unroll
    for (int off = 32; off > 0; off >>= 1) s += __shfl_down(s, off, 64);
    if (lane == 0) sm4[wid] = s;
    __syncthreads();
    if (t == 0) s_s = sm4[0] + sm4[1] + sm4[2] + sm4[3];
    __syncthreads();
    const float inv = 1.0f / s_s;
    y[t] = e0 * inv;
    y[t + 256] = e1 * inv;
    y[t + 512] = e2 * inv;
    if (has3) y[t + 768] = e3 * inv;
}

extern "C" void kernel_launch(void* const* d_in, const int* in_sizes, int n_in,
                              void* d_out, int out_size, void* d_ws, size_t ws_size,
                              hipStream_t stream)
{
    const float* features = (const float*)d_in[0];  // [8192,2048]
    const float* W_b      = (const float*)d_in[1];  // [1024,2048]
    const float* b_b      = (const float*)d_in[2];  // [1024]
    const float* W1       = (const float*)d_in[3];  // [1000,1024]
    const float* W2       = (const float*)d_in[4];  // [1000,1024]
    const float* centroid = (const float*)d_in[5];  // [1000,1024]

    char* base = (char*)d_out;
    float* feats = (float*)(base);
    float* aug   = (float*)(base + 33554432);
    float* o1    = (float*)(base + 67108864);
    float* o2    = (float*)(base + 99876864);
    float* smx   = (float*)(base + 132644864);

    _Float16* fh    = (_Float16*)(base + 67108864);
    _Float16* fetsh = (_Float16*)(base + 33554432);
    float*    P1    = (float*)   (base + 33554432);
    float*    P2    = (float*)   (base + 33554432);
    int*      idx   = (int*)     (base + 50331648);
    int*      cnt   = (int*)     (base + 50339840);
    _Float16* fgsh  = (_Float16*)(base + 50348032);
    _Float16* fgsl  = (_Float16*)(base + 52445184);
    _Float16* sm1c  = (_Float16*)(base + 99876864);
    int*      pidx  = (int*)     (base + 108265472);
    float*    pw    = (float*)   (base + 108298240);
    _Float16* cthc  = (_Float16*)(base + 116654080);
    _Float16* wbh   = (_Float16*)(base + 118751232);
    _Float16* wbl   = (_Float16*)(base + 122945536);
    _Float16* w2h   = (_Float16*)(base + 132644864);
    _Float16* w1h   = (_Float16*)(base + 142606336);
    _Float16* w1l   = (_Float16*)(base + 144703488);
    _Float16* fgh   = (_Float16*)(base + 146800640);
    _Float16* fgl   = (_Float16*)(base + 150994944);
    _Float16* xh    = (_Float16*)(base + 146800640);

    // 1: all conversions + cnt=0
    prep_kernel<<<5632, 256, 0, stream>>>(features, fh, W_b, wbh, wbl,
                                          W1, w1h, w1l, W2, w2h, centroid, cthc, cnt);
    // 2: G1 feats = F@W_b^T + b_b; epilogue also emits fetsh
    gemm16<1><<<512, 256, 0, stream>>>(fh, 2048, wbh, 2048, 2048,
                                       feats, 1024, 1024, b_b, fetsh,
                                       nullptr, nullptr, nullptr);
    // 3: G2 o1 = feats@W1^T
    gemm16<2><<<512, 256, 0, stream>>>(fetsh, 1024, w1h, 1024, 1024,
                                       o1, 1000, 1000, nullptr, nullptr,
                                       nullptr, nullptr, nullptr);
    // 4: masked softmax (compact) + flagging + fused gather
    masksm_kernel<<<8192, 256, 0, stream>>>(o1, sm1c, pw, pidx, features,
                                            fgh, fgl, idx, cnt);
    // 5-8: correction chain (flagged rows only; blocks early-exit on cnt)
    gemmc<<<dim3(8, CAP / 128, 4), 256, 0, stream>>>(fgh, fgl, 2048, wbh, wbl, 2048, 512,
                                                     P1, 1024, 1024, cnt);
    red1_kernel<<<CAP, 256, 0, stream>>>(P1, b_b, fgsh, fgsl, cnt);
    gemmc<<<dim3(8, CAP / 128, 4), 256, 0, stream>>>(fgsh, fgsl, 1024, w1h, w1l, 1024, 256,
                                                     P2, 1000, 1000, cnt);
    fixup_kernel<<<CAP, 256, 0, stream>>>(P2, sm1c, pw, pidx, idx, cnt);
    // 9: G3' aug = sm1c@cthc^T (K=512) + feats + pw*centroid[pidx]
    gemm16<3><<<512, 256, 0, stream>>>(sm1c, 512, cthc, 512, 512,
                                       aug, 1024, 1024, feats, nullptr,
                                       centroid, pidx, pw);
    // 10: rownorm + x conversion
    rownorm_x_kernel<<<8192, 256, 0, stream>>>(aug, xh);
    // 11: G4 o2 = x@W2^T * 20
    gemm16<4><<<512, 256, 0, stream>>>(xh, 1024, w2h, 1024, 1024,
                                       o2, 1000, 1000, nullptr, nullptr,
                                       nullptr, nullptr, nullptr);
    // 12: final softmax
    softmax2_kernel<<<8192, 256, 0, stream>>>(o2, smx);
}

// Round 10
// 258.211 us; speedup vs baseline: 1.2079x; 1.0078x over previous
//
#include <hip/hip_runtime.h>
#include <cmath>

// ---------------------------------------------------------------------------
// Classifier pipeline, round 10.
// Main GEMMs: fp16x1 m97 structure. G3 uses sm1 structure: dense K=512
// (compacted private classes) + per-row rank-1 pw*centroid[pidx] (fp32 exact).
// Argmax protected by fp16x2 correction chain on flagged rows (top-2 gap
// < TAU), K-split z=8 partials (latency-bound dispatch shrink).
//
// d_out byte layout (total 165,412,864 B):
//   feats [8192,1024] f32 @ 0
//   aug   [8192,1024] f32 @ 33,554,432
//   o1    [8192,1000] f32 @ 67,108,864
//   o2    [8192,1000] f32 @ 99,876,864
//   smx   [8192,1000] f32 @ 132,644,864
//
// Scratch (dead-region hosted; lifetime [first-write .. last-read]):
//   fh    fp16[8192*2048] @  67,108,864  [prep .. G1]        (o1 slot)
//   fetsh fp16[8192*1024] @  33,554,432  [G1 .. G2]          (aug slot)
//   P1    f32[8*1024*1024]@  33,554,432  [gG1 .. red1]       (ends 67,108,864)
//   P2    f32[8*1024*1000]@  33,554,432  [gG2 .. fixup]      (ends 66,314,240)
//   sm1c  fp16[8192*512]  @  99,876,864  [masksm .. G3]      (o2 slot)
//   pidx  int[8192]       @ 108,265,472  [masksm .. G3]
//   pw    f32[8192]       @ 108,298,240  [masksm .. G3]
//   cthc  fp16[1024*512]  @ 116,654,080  [prep .. G3]
//   wbh   fp16[1024*2048] @ 118,751,232  [prep .. gG1]
//   wbl   fp16[1024*2048] @ 122,945,536  [prep .. gG1]
//   w2h   fp16[1024*1024] @ 132,644,864  [prep .. G4]        (smx slot)
//   w1h   fp16[1024*1024] @ 142,606,336  [prep .. gG2]
//   w1l   fp16[1024*1024] @ 144,703,488  [prep .. gG2]
//   fgh   fp16[1024*2048] @ 146,800,640  [masksm .. gG1]
//   fgl   fp16[1024*2048] @ 150,994,944  [masksm .. gG1]     (ends 155,189,248)
//   idx   int[1024]       @ 155,189,248  [masksm .. fixup]
//   cnt   int             @ 155,193,344  [prep .. fixup]
//   fgsh  fp16[1024*1024] @ 155,197,440  [red1 .. gG2]
//   fgsl  fp16[1024*1024] @ 157,294,592  [red1 .. gG2]       (ends 159,391,744)
//   xh    fp16[8192*1024] @ 146,800,640  [rownorm .. G4]     (fg*/idx/fgs* dead)
// ---------------------------------------------------------------------------

typedef _Float16 h8 __attribute__((ext_vector_type(8)));
typedef _Float16 h4 __attribute__((ext_vector_type(4)));
typedef float f32x4 __attribute__((ext_vector_type(4)));

#define TAU 0.008f
#define CAP 1024

__device__ __forceinline__ void gload_lds16(const _Float16* g, _Float16* l) {
    __builtin_amdgcn_global_load_lds(
        (const __attribute__((address_space(1))) void*)g,
        (__attribute__((address_space(3))) void*)l, 16, 0, 0);
}

__device__ __forceinline__ void split4(f32x4 v, h4& h, h4& l) {
    #pragma unroll
    for (int j = 0; j < 4; ++j) {
        _Float16 hh = (_Float16)v[j];
        h[j] = hh;
        l[j] = (_Float16)((v[j] - (float)hh) * 2048.0f);
    }
}

// ===========================================================================
// prep: cnt=0 + conv(features) + split(W_b) + padsplit(W1) + ctransc + pad(W2)
// sections: [0,4096) conv | [4096,5120) Wb | [5120,6144) W1
//           [6144,6656) ctransc | [6656,7680) W2
// ===========================================================================
__global__ __launch_bounds__(256) void prep_kernel(
    const float* __restrict__ features, _Float16* __restrict__ fh,
    const float* __restrict__ W_b, _Float16* __restrict__ wbh, _Float16* __restrict__ wbl,
    const float* __restrict__ W1, _Float16* __restrict__ w1h, _Float16* __restrict__ w1l,
    const float* __restrict__ W2, _Float16* __restrict__ w2h,
    const float* __restrict__ centroid, _Float16* __restrict__ cthc,
    int* __restrict__ cnt)
{
    __shared__ float tile[32][33];
    const int bid = blockIdx.x;
    const int t = threadIdx.x;
    if (bid == 0 && t == 0) *cnt = 0;

    if (bid < 4096) {
        #pragma unroll
        for (int q = 0; q < 4; ++q) {
            const int i = (bid * 256 + t) + q * 4096 * 256;
            f32x4 v = ((const f32x4*)features)[i];
            h4 h;
            #pragma unroll
            for (int j = 0; j < 4; ++j) h[j] = (_Float16)v[j];
            ((h4*)fh)[i] = h;
        }
    } else if (bid < 5120) {
        const int i = (bid - 4096) * 512 + t;
        #pragma unroll
        for (int q = 0; q < 2; ++q) {
            const int k = i + q * 256;
            f32x4 v = ((const f32x4*)W_b)[k];
            h4 h, l; split4(v, h, l);
            ((h4*)wbh)[k] = h;
            ((h4*)wbl)[k] = l;
        }
    } else if (bid < 6144) {
        const int i = (bid - 5120) * 256 + t;
        const int r = i >> 8;
        f32x4 v = {0.f, 0.f, 0.f, 0.f};
        if (r < 1000) v = ((const f32x4*)W1)[i];
        h4 h, l; split4(v, h, l);
        ((h4*)w1h)[i] = h;
        ((h4*)w1l)[i] = l;
    } else if (bid < 6656) {
        // cthc[n][k] = k<500 ? centroid[500+k][n] : 0   (n:1024, k:512)
        const int local = bid - 6144;
        const int n0 = (local & 31) * 32, k0 = (local >> 5) * 32;
        const int tx = t & 31, ty = t >> 5;
        #pragma unroll
        for (int p = 0; p < 4; ++p) {
            int k = k0 + ty + p * 8;
            tile[ty + p * 8][tx] = (k < 500) ? centroid[(size_t)(500 + k) * 1024 + n0 + tx] : 0.0f;
        }
        __syncthreads();
        #pragma unroll
        for (int p = 0; p < 4; ++p) {
            int n = n0 + ty + p * 8;
            cthc[(size_t)n * 512 + k0 + tx] = (_Float16)tile[tx][ty + p * 8];
        }
    } else {
        const int i = (bid - 6656) * 256 + t;
        const int r = i >> 8;
        f32x4 v = {0.f, 0.f, 0.f, 0.f};
        if (r < 1000) v = ((const f32x4*)W2)[i];
        h4 h;
        #pragma unroll
        for (int j = 0; j < 4; ++j) h[j] = (_Float16)v[j];
        ((h4*)w2h)[i] = h;
    }
}

// ===========================================================================
// Main GEMM (m97 structure, fp16x1), 128x128 tile, 4 waves, gload_lds.
// MODE 1: C = A@B^T + bias(aux); also Ch = fp16(C)
// MODE 2: C = A@B^T, cols<nC
// MODE 3: C = A@B^T + aux[row,col] + pw[row]*cent[pidx[row]][col]
// MODE 4: C = A@B^T * 20, cols<nC
// ===========================================================================
template <int MODE>
__global__ __launch_bounds__(256, 4) void gemm16(
    const _Float16* __restrict__ Ah, int lda,
    const _Float16* __restrict__ Bh, int ldb, int K,
    float* __restrict__ C, int ldc, int nC,
    const float* __restrict__ aux, _Float16* __restrict__ Ch,
    const float* __restrict__ cent, const int* __restrict__ pidx,
    const float* __restrict__ pw)
{
    __shared__ _Float16 sAh[128 * 64];
    __shared__ _Float16 sBh[128 * 64];

    const int t = threadIdx.x;
    const int lane = t & 63, wid = t >> 6;
    // bijective XCD swizzle (512 wgs, 64/XCD -> 8 row-panels x 8 col)
    const int wg = blockIdx.x;
    const int wgid = (wg & 7) * 64 + (wg >> 3);
    const int row0 = (wgid >> 3) * 128, col0 = (wgid & 7) * 128;
    const int wr = wid >> 1, wc = wid & 1;
    const int fr = lane & 15;
    const int fk = (lane >> 4) * 8;
    const int srow = lane >> 3;
    const int scol = (lane & 7) * 8;

    f32x4 acc[4][4] = {};

    for (int k0 = 0; k0 < K; k0 += 64) {
        #pragma unroll
        for (int j = 0; j < 4; ++j) {
            int i = wid * 4 + j;
            int r = i * 8 + srow;
            gload_lds16(Ah + (size_t)(row0 + r) * lda + k0 + scol, &sAh[i * 512]);
            gload_lds16(Bh + (size_t)(col0 + r) * ldb + k0 + scol, &sBh[i * 512]);
        }
        __syncthreads();
        #pragma unroll
        for (int ks = 0; ks < 2; ++ks) {
            h8 ah[4];
            #pragma unroll
            for (int mf = 0; mf < 4; ++mf)
                ah[mf] = *(const h8*)&sAh[(wr * 64 + mf * 16 + fr) * 64 + ks * 32 + fk];
            #pragma unroll
            for (int nf = 0; nf < 4; ++nf) {
                h8 bh = *(const h8*)&sBh[(wc * 64 + nf * 16 + fr) * 64 + ks * 32 + fk];
                #pragma unroll
                for (int mf = 0; mf < 4; ++mf)
                    acc[mf][nf] = __builtin_amdgcn_mfma_f32_16x16x32_f16(ah[mf], bh, acc[mf][nf], 0, 0, 0);
            }
        }
        __syncthreads();
    }
    #pragma unroll
    for (int mf = 0; mf < 4; ++mf) {
        #pragma unroll
        for (int nf = 0; nf < 4; ++nf) {
            f32x4 v = acc[mf][nf];
            const int gcol = col0 + wc * 64 + nf * 16 + fr;
            const int rbase = row0 + wr * 64 + mf * 16 + (lane >> 4) * 4;
            #pragma unroll
            for (int j = 0; j < 4; ++j) {
                const int grow = rbase + j;
                float val = v[j];
                if constexpr (MODE == 1) val += aux[gcol];
                if constexpr (MODE == 3) {
                    const int p = pidx[grow];
                    val += aux[(size_t)grow * 1024 + gcol]
                         + pw[grow] * cent[(size_t)p * 1024 + gcol];
                }
                if constexpr (MODE == 4) val *= 20.0f;
                if (gcol < nC) {
                    C[(size_t)grow * ldc + gcol] = val;
                    if constexpr (MODE == 1)
                        Ch[(size_t)grow * 1024 + gcol] = (_Float16)val;
                }
            }
        }
    }
}

// ===========================================================================
// Chain GEMM (m97, fp16x2, K-split partials via blockIdx.z, early-exit)
// ===========================================================================
__global__ __launch_bounds__(256, 2) void gemmc(
    const _Float16* __restrict__ Ah, const _Float16* __restrict__ Al, int lda,
    const _Float16* __restrict__ Bh, const _Float16* __restrict__ Bl, int ldb,
    int klen,
    float* __restrict__ C, int ldc, int nC,
    const int* __restrict__ cnt)
{
    __shared__ _Float16 sAh[128 * 64];
    __shared__ _Float16 sBh[128 * 64];
    __shared__ _Float16 sAl[128 * 64];
    __shared__ _Float16 sBl[128 * 64];

    const int t = threadIdx.x;
    const int lane = t & 63, wid = t >> 6;
    const int row0 = blockIdx.y * 128, col0 = blockIdx.x * 128;
    const int kbase = blockIdx.z * klen;
    if (row0 >= *cnt) return;
    const int wr = wid >> 1, wc = wid & 1;
    const int fr = lane & 15;
    const int fk = (lane >> 4) * 8;
    const int srow = lane >> 3;
    const int scol = (lane & 7) * 8;

    f32x4 acc[4][4] = {};
    f32x4 accc[4][4] = {};

    for (int k0 = kbase; k0 < kbase + klen; k0 += 64) {
        #pragma unroll
        for (int j = 0; j < 4; ++j) {
            int i = wid * 4 + j;
            int r = i * 8 + srow;
            const size_t ga = (size_t)(row0 + r) * lda + k0 + scol;
            const size_t gb = (size_t)(col0 + r) * ldb + k0 + scol;
            gload_lds16(Ah + ga, &sAh[i * 512]);
            gload_lds16(Bh + gb, &sBh[i * 512]);
            gload_lds16(Al + ga, &sAl[i * 512]);
            gload_lds16(Bl + gb, &sBl[i * 512]);
        }
        __syncthreads();
        #pragma unroll
        for (int ks = 0; ks < 2; ++ks) {
            h8 ah[4], al[4];
            #pragma unroll
            for (int mf = 0; mf < 4; ++mf) {
                int rr = wr * 64 + mf * 16 + fr;
                ah[mf] = *(const h8*)&sAh[rr * 64 + ks * 32 + fk];
                al[mf] = *(const h8*)&sAl[rr * 64 + ks * 32 + fk];
            }
            #pragma unroll
            for (int nf = 0; nf < 4; ++nf) {
                int cc = wc * 64 + nf * 16 + fr;
                h8 bh = *(const h8*)&sBh[cc * 64 + ks * 32 + fk];
                h8 bl = *(const h8*)&sBl[cc * 64 + ks * 32 + fk];
                #pragma unroll
                for (int mf = 0; mf < 4; ++mf) {
                    acc[mf][nf]  = __builtin_amdgcn_mfma_f32_16x16x32_f16(ah[mf], bh, acc[mf][nf], 0, 0, 0);
                    accc[mf][nf] = __builtin_amdgcn_mfma_f32_16x16x32_f16(ah[mf], bl, accc[mf][nf], 0, 0, 0);
                    accc[mf][nf] = __builtin_amdgcn_mfma_f32_16x16x32_f16(al[mf], bh, accc[mf][nf], 0, 0, 0);
                }
            }
        }
        __syncthreads();
    }
    float* Cz = C + (size_t)blockIdx.z * CAP * ldc;
    #pragma unroll
    for (int mf = 0; mf < 4; ++mf) {
        #pragma unroll
        for (int nf = 0; nf < 4; ++nf) {
            f32x4 v = acc[mf][nf] + accc[mf][nf] * (1.0f / 2048.0f);
            const int gcol = col0 + wc * 64 + nf * 16 + fr;
            const int rbase = row0 + wr * 64 + mf * 16 + (lane >> 4) * 4;
            #pragma unroll
            for (int j = 0; j < 4; ++j) {
                if (gcol < nC) Cz[(size_t)(rbase + j) * ldc + gcol] = v[j];
            }
        }
    }
}

// shared device body: masked softmax on logits x (len 1000) -> COMPACT outputs:
// y[512] = sm1 over classes 500..999 (zeros if one-hot), pw/pidx rank-1 term.
__device__ __forceinline__ void masked_softmax_body(
    const float* __restrict__ x, _Float16* __restrict__ y,
    float* __restrict__ pwp, int* __restrict__ pidxp,
    int t, float* wv, int* wi, bool flag, int* d_idx, int* d_cnt, int rowid,
    int* s_slot)
{
    float bv = -1e30f, sv = -1e30f; int bi = 0;
    for (int c = t; c < 1000; c += 256) {
        float v = x[c];
        if (v > bv) { sv = bv; bv = v; bi = c; }
        else if (v > sv) sv = v;
    }
    #pragma unroll
    for (int off = 32; off > 0; off >>= 1) {
        float ov = __shfl_down(bv, off, 64);
        int   oi = __shfl_down(bi, off, 64);
        float os = __shfl_down(sv, off, 64);
        if (ov > bv || (ov == bv && oi < bi)) {
            sv = fmaxf(bv, os); bv = ov; bi = oi;
        } else {
            sv = fmaxf(sv, fmaxf(ov, os) == ov ? ov : os);
            sv = fmaxf(sv, ov); sv = fmaxf(sv, os);
        }
    }
    __shared__ float svv[4];
    const int lane = t & 63, wid = t >> 6;
    if (lane == 0) { wv[wid] = bv; wi[wid] = bi; svv[wid] = sv; }
    __syncthreads();
    __shared__ float s_m, s_tot; __shared__ int s_p;
    if (t == 0) {
        float mv = wv[0]; int mi = wi[0]; float m2 = svv[0];
        for (int w = 1; w < 4; ++w) {
            if (wv[w] > mv || (wv[w] == mv && wi[w] < mi)) {
                m2 = fmaxf(mv, svv[w]); mv = wv[w]; mi = wi[w];
            } else {
                m2 = fmaxf(m2, fmaxf(wv[w], svv[w]));
            }
        }
        s_p = mi; s_m = mv;
        int slot = -1;
        if (flag && (mv - m2) < TAU) {
            int q = atomicAdd(d_cnt, 1);
            if (q < CAP) { d_idx[q] = rowid; slot = q; }
        }
        *s_slot = slot;
    }
    __syncthreads();
    const int p = s_p; const float m = s_m;
    if (p >= 500) {
        for (int c = t; c < 512; c += 256) y[c] = (_Float16)0.0f;
        if (t == 0) { pwp[0] = 1.0f; pidxp[0] = p; }
    } else {
        float s = 0.f;
        for (int c = t; c < 1000; c += 256)
            if (c == p || c >= 500) s += expf(x[c] - m);
        #pragma unroll
        for (int off = 32; off > 0; off >>= 1) s += __shfl_down(s, off, 64);
        if (lane == 0) wv[wid] = s;
        __syncthreads();
        if (t == 0) s_tot = wv[0] + wv[1] + wv[2] + wv[3];
        __syncthreads();
        const float inv = 1.0f / s_tot;
        for (int c = t; c < 512; c += 256) {
            float v = 0.f;
            if (c < 500) v = expf(x[500 + c] - m) * inv;
            y[c] = (_Float16)v;
        }
        if (t == 0) { pwp[0] = inv; pidxp[0] = p; }  // sm1[p] = exp(0)*inv = inv
    }
}

// masked softmax + flagging + fused feature gather; LDS-cached logit row
__global__ __launch_bounds__(256) void masksm_kernel(
    const float* __restrict__ o1, _Float16* __restrict__ sm1c,
    float* __restrict__ pwa, int* __restrict__ pidxa,
    const float* __restrict__ features,
    _Float16* __restrict__ fgh, _Float16* __restrict__ fgl,
    int* __restrict__ d_idx, int* __restrict__ d_cnt)
{
    __shared__ float xs[1000];
    __shared__ float wv[4]; __shared__ int wi[4]; __shared__ int s_slot;
    const int row = blockIdx.x;
    const int t = threadIdx.x;
    const float* x = o1 + (size_t)row * 1000;
    for (int c = t; c < 1000; c += 256) xs[c] = x[c];
    __syncthreads();
    masked_softmax_body(xs, sm1c + (size_t)row * 512, pwa + row, pidxa + row,
                        t, wv, wi, true, d_idx, d_cnt, row, &s_slot);
    const int slot = s_slot;
    if (slot >= 0) {
        #pragma unroll
        for (int q = 0; q < 2; ++q) {
            int o = t * 8 + q * 4;
            f32x4 v = *(const f32x4*)(features + (size_t)row * 2048 + o);
            h4 h, l; split4(v, h, l);
            *(h4*)(fgh + (size_t)slot * 2048 + o) = h;
            *(h4*)(fgl + (size_t)slot * 2048 + o) = l;
        }
    }
}

// fixup: sum 8 P2 partials, then precise masked-softmax rewrite (compact)
__global__ __launch_bounds__(256) void fixup_kernel(
    const float* __restrict__ P2, _Float16* __restrict__ sm1c,
    float* __restrict__ pwa, int* __restrict__ pidxa,
    const int* __restrict__ d_idx, const int* __restrict__ d_cnt)
{
    const int slot = blockIdx.x;
    if (slot >= *d_cnt || slot >= CAP) return;
    const int row = d_idx[slot];
    const int t = threadIdx.x;
    __shared__ float xr[1000];
    for (int c = t; c < 1000; c += 256) {
        const size_t o = (size_t)slot * 1000 + c;
        float s = 0.f;
        #pragma unroll
        for (int z = 0; z < 8; ++z) s += P2[o + (size_t)z * CAP * 1000];
        xr[c] = s;
    }
    __syncthreads();
    __shared__ float wv[4]; __shared__ int wi[4]; __shared__ int s_slot;
    masked_softmax_body(xr, sm1c + (size_t)row * 512, pwa + row, pidxa + row,
                        t, wv, wi, false, nullptr, nullptr, 0, &s_slot);
}

// red1: fgs = split( sum_z P1[z] + bias )
__global__ __launch_bounds__(256) void red1_kernel(const float* __restrict__ P1,
                                                   const float* __restrict__ bias,
                                                   _Float16* __restrict__ fgsh,
                                                   _Float16* __restrict__ fgsl,
                                                   const int* __restrict__ d_cnt)
{
    const int slot = blockIdx.x;
    if (slot >= *d_cnt || slot >= CAP) return;
    const int t = threadIdx.x;
    #pragma unroll
    for (int q = 0; q < 4; ++q) {
        const int c = t + q * 256;
        const size_t o = (size_t)slot * 1024 + c;
        float s = bias[c];
        #pragma unroll
        for (int z = 0; z < 8; ++z) s += P1[o + (size_t)z * CAP * 1024];
        _Float16 h = (_Float16)s;
        fgsh[o] = h;
        fgsl[o] = (_Float16)((s - (float)h) * 2048.0f);
    }
}

// fused: invn = 1/max(||aug_row||,eps); xh = fp16(aug * invn)
__global__ __launch_bounds__(256) void rownorm_x_kernel(const float* __restrict__ aug,
                                                        _Float16* __restrict__ xh)
{
    const int row = blockIdx.x; const int t = threadIdx.x;
    f32x4 v = *((const f32x4*)(aug + (size_t)row * 1024) + t);
    float s = v[0]*v[0] + v[1]*v[1] + v[2]*v[2] + v[3]*v[3];
    #pragma unroll
    for (int off = 32; off > 0; off >>= 1) s += __shfl_down(s, off, 64);
    __shared__ float ws4[4]; __shared__ float s_inv;
    const int lane = t & 63, wid = t >> 6;
    if (lane == 0) ws4[wid] = s;
    __syncthreads();
    if (t == 0) {
        float tot = ws4[0] + ws4[1] + ws4[2] + ws4[3];
        s_inv = 1.0f / fmaxf(sqrtf(tot), 1e-12f);
    }
    __syncthreads();
    const float inv = s_inv;
    h4 h;
    #pragma unroll
    for (int j = 0; j < 4; ++j) h[j] = (_Float16)(v[j] * inv);
    *((h4*)(xh + (size_t)row * 1024) + t) = h;
}

// row softmax over 1000, register-resident (4 values/thread, 1 read, 1 expf)
__global__ __launch_bounds__(256) void softmax2_kernel(const float* __restrict__ o2,
                                                       float* __restrict__ out)
{
    const int row = blockIdx.x; const int t = threadIdx.x;
    const float* x = o2 + (size_t)row * 1000;
    float* y = out + (size_t)row * 1000;
    const bool has3 = (t < 232);
    float v0 = x[t], v1 = x[t + 256], v2 = x[t + 512];
    float v3 = has3 ? x[t + 768] : -1e30f;
    float m = fmaxf(fmaxf(v0, v1), fmaxf(v2, v3));
    #pragma unroll
    for (int off = 32; off > 0; off >>= 1) m = fmaxf(m, __shfl_down(m, off, 64));
    __shared__ float sm4[4]; __shared__ float s_m, s_s;
    const int lane = t & 63, wid = t >> 6;
    if (lane == 0) sm4[wid] = m;
    __syncthreads();
    if (t == 0) s_m = fmaxf(fmaxf(sm4[0], sm4[1]), fmaxf(sm4[2], sm4[3]));
    __syncthreads();
    m = s_m;
    float e0 = expf(v0 - m), e1 = expf(v1 - m), e2 = expf(v2 - m);
    float e3 = has3 ? expf(v3 - m) : 0.0f;
    float s = (e0 + e1) + (e2 + e3);
    #pragma unroll
    for (int off = 32; off > 0; off >>= 1) s += __shfl_down(s, off, 64);
    if (lane == 0) sm4[wid] = s;
    __syncthreads();
    if (t == 0) s_s = sm4[0] + sm4[1] + sm4[2] + sm4[3];
    __syncthreads();
    const float inv = 1.0f / s_s;
    y[t] = e0 * inv;
    y[t + 256] = e1 * inv;
    y[t + 512] = e2 * inv;
    if (has3) y[t + 768] = e3 * inv;
}

extern "C" void kernel_launch(void* const* d_in, const int* in_sizes, int n_in,
                              void* d_out, int out_size, void* d_ws, size_t ws_size,
                              hipStream_t stream)
{
    const float* features = (const float*)d_in[0];  // [8192,2048]
    const float* W_b      = (const float*)d_in[1];  // [1024,2048]
    const float* b_b      = (const float*)d_in[2];  // [1024]
    const float* W1       = (const float*)d_in[3];  // [1000,1024]
    const float* W2       = (const float*)d_in[4];  // [1000,1024]
    const float* centroid = (const float*)d_in[5];  // [1000,1024]

    char* base = (char*)d_out;
    float* feats = (float*)(base);
    float* aug   = (float*)(base + 33554432);
    float* o1    = (float*)(base + 67108864);
    float* o2    = (float*)(base + 99876864);
    float* smx   = (float*)(base + 132644864);

    _Float16* fh    = (_Float16*)(base + 67108864);
    _Float16* fetsh = (_Float16*)(base + 33554432);
    float*    P1    = (float*)   (base + 33554432);
    float*    P2    = (float*)   (base + 33554432);
    _Float16* sm1c  = (_Float16*)(base + 99876864);
    int*      pidx  = (int*)     (base + 108265472);
    float*    pw    = (float*)   (base + 108298240);
    _Float16* cthc  = (_Float16*)(base + 116654080);
    _Float16* wbh   = (_Float16*)(base + 118751232);
    _Float16* wbl   = (_Float16*)(base + 122945536);
    _Float16* w2h   = (_Float16*)(base + 132644864);
    _Float16* w1h   = (_Float16*)(base + 142606336);
    _Float16* w1l   = (_Float16*)(base + 144703488);
    _Float16* fgh   = (_Float16*)(base + 146800640);
    _Float16* fgl   = (_Float16*)(base + 150994944);
    int*      idx   = (int*)     (base + 155189248);
    int*      cnt   = (int*)     (base + 155193344);
    _Float16* fgsh  = (_Float16*)(base + 155197440);
    _Float16* fgsl  = (_Float16*)(base + 157294592);
    _Float16* xh    = (_Float16*)(base + 146800640);

    // 1: all conversions + cnt=0
    prep_kernel<<<7680, 256, 0, stream>>>(features, fh, W_b, wbh, wbl,
                                          W1, w1h, w1l, W2, w2h, centroid, cthc, cnt);
    // 2: G1 feats = F@W_b^T + b_b; epilogue also emits fetsh
    gemm16<1><<<512, 256, 0, stream>>>(fh, 2048, wbh, 2048, 2048,
                                       feats, 1024, 1024, b_b, fetsh,
                                       nullptr, nullptr, nullptr);
    // 3: G2 o1 = feats@W1^T
    gemm16<2><<<512, 256, 0, stream>>>(fetsh, 1024, w1h, 1024, 1024,
                                       o1, 1000, 1000, nullptr, nullptr,
                                       nullptr, nullptr, nullptr);
    // 4: masked softmax (compact) + flagging + fused gather
    masksm_kernel<<<8192, 256, 0, stream>>>(o1, sm1c, pw, pidx, features,
                                            fgh, fgl, idx, cnt);
    // 5-8: correction chain (flagged rows only; blocks early-exit on cnt)
    gemmc<<<dim3(8, CAP / 128, 8), 256, 0, stream>>>(fgh, fgl, 2048, wbh, wbl, 2048, 256,
                                                     P1, 1024, 1024, cnt);
    red1_kernel<<<CAP, 256, 0, stream>>>(P1, b_b, fgsh, fgsl, cnt);
    gemmc<<<dim3(8, CAP / 128, 8), 256, 0, stream>>>(fgsh, fgsl, 1024, w1h, w1l, 1024, 128,
                                                     P2, 1000, 1000, cnt);
    fixup_kernel<<<CAP, 256, 0, stream>>>(P2, sm1c, pw, pidx, idx, cnt);
    // 9: G3' aug = sm1c@cthc^T (K=512) + feats + pw*centroid[pidx]
    gemm16<3><<<512, 256, 0, stream>>>(sm1c, 512, cthc, 512, 512,
                                       aug, 1024, 1024, feats, nullptr,
                                       centroid, pidx, pw);
    // 10: rownorm + x conversion
    rownorm_x_kernel<<<8192, 256, 0, stream>>>(aug, xh);
    // 11: G4 o2 = x@W2^T * 20
    gemm16<4><<<512, 256, 0, stream>>>(xh, 1024, w2h, 1024, 1024,
                                       o2, 1000, 1000, nullptr, nullptr,
                                       nullptr, nullptr, nullptr);
    // 12: final softmax
    softmax2_kernel<<<8192, 256, 0, stream>>>(o2, smx);
}